// Round 2
// baseline (907.333 us; speedup 1.0000x reference)
//
#include <hip/hip_runtime.h>
#include <cstdint>
#include <cstddef>

#define NN 50000

// ---------------- small utility kernels ----------------

__global__ __launch_bounds__(256) void k_set1(float* __restrict__ p, int n) {
  int i = blockIdx.x * 256 + threadIdx.x;
  if (i < n) p[i] = 1.0f;
}

__global__ __launch_bounds__(256) void k_deg(const int* __restrict__ dst,
                                             const float* __restrict__ ew,
                                             float* __restrict__ deg, int E) {
  int e = blockIdx.x * 256 + threadIdx.x;
  if (e < E) atomicAdd(&deg[dst[e]], ew[e]);
}

__global__ __launch_bounds__(256) void k_rsqrt(float* __restrict__ p, int n) {
  int i = blockIdx.x * 256 + threadIdx.x;
  if (i < n) p[i] = rsqrtf(p[i]);
}

__global__ __launch_bounds__(256) void k_norm(const int* __restrict__ src,
                                              const int* __restrict__ dst,
                                              const float* __restrict__ ew,
                                              const float* __restrict__ dis,
                                              float* __restrict__ nrm, int E) {
  int e = blockIdx.x * 256 + threadIdx.x;
  if (e < E) nrm[e] = dis[src[e]] * ew[e] * dis[dst[e]];
}

// ---------------- fp32 tiled GEMM: C[N,F] = A[N,K] @ B[K,F] ----------------
// BM=BN=BK=64, 256 threads, 4x4 micro-tile per thread.
// A staged transposed in LDS so the fragment read is one ds_read_b128.

__global__ __launch_bounds__(256) void k_gemm(const float* __restrict__ A, int lda,
                                              const float* __restrict__ B, int ldb,
                                              float* __restrict__ C, int ldc,
                                              int N, int K) {
  __shared__ float As[64][68];  // [k][m], padded
  __shared__ float Bs[64][68];  // [k][n]
  const int tid = threadIdx.x;
  const int bm = blockIdx.x * 64;
  const int bn = blockIdx.y * 64;
  const int tx = tid & 15;      // n-direction
  const int ty = tid >> 4;      // m-direction
  float acc[4][4] = {};

  for (int kt = 0; kt < K; kt += 64) {
#pragma unroll
    for (int p = 0; p < 4; ++p) {
      int s = tid + p * 256;          // 0..1023 float4 slots
      int r = s >> 4;                 // tile row 0..63
      int c4 = (s & 15) << 2;         // tile col {0,4,...,60}
      // A tile (rows = M, cols = K) -> store transposed
      float4 va = make_float4(0.f, 0.f, 0.f, 0.f);
      int gr = bm + r;
      if (gr < N) va = *(const float4*)(A + (size_t)gr * lda + kt + c4);
      As[c4 + 0][r] = va.x;
      As[c4 + 1][r] = va.y;
      As[c4 + 2][r] = va.z;
      As[c4 + 3][r] = va.w;
      // B tile (rows = K, cols = F) -> store as-is
      float4 vb = *(const float4*)(B + (size_t)(kt + r) * ldb + bn + c4);
      *(float4*)(&Bs[r][c4]) = vb;
    }
    __syncthreads();
#pragma unroll
    for (int kk = 0; kk < 64; ++kk) {
      float4 a4 = *(const float4*)(&As[kk][ty * 4]);
      float4 b4 = *(const float4*)(&Bs[kk][tx * 4]);
      float a[4] = {a4.x, a4.y, a4.z, a4.w};
      float b[4] = {b4.x, b4.y, b4.z, b4.w};
#pragma unroll
      for (int i = 0; i < 4; ++i)
#pragma unroll
        for (int j = 0; j < 4; ++j) acc[i][j] += a[i] * b[j];
    }
    __syncthreads();
  }

#pragma unroll
  for (int i = 0; i < 4; ++i) {
    int gr = bm + ty * 4 + i;
    if (gr < N) {
      float4 v = make_float4(acc[i][0], acc[i][1], acc[i][2], acc[i][3]);
      *(float4*)(C + (size_t)gr * ldc + bn + tx * 4) = v;
    }
  }
}

// ---------------- aggregation ----------------
// out[n, coloff+f] = bias[f] + dis[n]^2 * t[n,f]   (self-loop + bias, full init)
template <int LOGF>
__global__ __launch_bounds__(256) void k_agg_init(const float* __restrict__ t,
                                                  const float* __restrict__ dis,
                                                  const float* __restrict__ bias,
                                                  float* __restrict__ out, int ldo,
                                                  int coloff, int n_total) {
  int idx = blockIdx.x * 256 + threadIdx.x;
  if (idx >= n_total) return;
  int n = idx >> LOGF;
  int f = idx & ((1 << LOGF) - 1);
  float d = dis[n];
  out[(size_t)n * ldo + coloff + f] = bias[f] + d * d * t[idx];
}

// out[dst[e], coloff+f] += norm[e] * t[src[e], f]
template <int LOGF>
__global__ __launch_bounds__(256) void k_agg_edges(const float* __restrict__ t,
                                                   const int* __restrict__ src,
                                                   const int* __restrict__ dst,
                                                   const float* __restrict__ nrm,
                                                   float* __restrict__ out, int ldo,
                                                   int coloff, int E) {
  constexpr int F = 1 << LOGF;
  constexpr int EPB = 256 >> LOGF;
  int e = blockIdx.x * EPB + (threadIdx.x >> LOGF);
  if (e >= E) return;
  int f = threadIdx.x & (F - 1);
  int s = src[e];
  int d = dst[e];
  float v = nrm[e] * t[(size_t)s * F + f];
  atomicAdd(&out[(size_t)d * ldo + coloff + f], v);
}

// ---------------- row softmax over 128 cols, one wave per row ----------------
__global__ __launch_bounds__(256) void k_softmax128(float* __restrict__ h, int N) {
  int row = blockIdx.x * 4 + (threadIdx.x >> 6);
  if (row >= N) return;
  int lane = threadIdx.x & 63;
  float* p = h + (size_t)row * 128;
  float v0 = p[lane];
  float v1 = p[lane + 64];
  float m = fmaxf(v0, v1);
#pragma unroll
  for (int o = 32; o > 0; o >>= 1) m = fmaxf(m, __shfl_xor(m, o));
  float e0 = __expf(v0 - m);
  float e1 = __expf(v1 - m);
  float sum = e0 + e1;
#pragma unroll
  for (int o = 32; o > 0; o >>= 1) sum += __shfl_xor(sum, o);
  float inv = 1.0f / sum;
  p[lane] = e0 * inv;
  p[lane + 64] = e1 * inv;
}

// ---------------- launch ----------------
extern "C" void kernel_launch(void* const* d_in, const int* in_sizes, int n_in,
                              void* d_out, int out_size, void* d_ws, size_t ws_size,
                              hipStream_t stream) {
  const float* x = (const float*)d_in[0];
  const int* ei = (const int*)d_in[1];   // harness delivers integer inputs as int32
  const float* ea = (const float*)d_in[2];
  const float* W1 = (const float*)d_in[3];
  const float* b1 = (const float*)d_in[4];
  const float* W2 = (const float*)d_in[5];
  const float* b2 = (const float*)d_in[6];
  const float* W3 = (const float*)d_in[7];
  const float* b3 = (const float*)d_in[8];

  const int N = NN;
  const int E = in_sizes[2];
  const int* src = ei;
  const int* dst = ei + E;

  char* ws = (char*)d_ws;
  size_t off = 0;
  auto alloc = [&](size_t bytes) {
    void* p = (void*)(ws + off);
    off += (bytes + 255) & ~(size_t)255;
    return p;
  };
  float* dis = (float*)alloc((size_t)N * 4);
  float* nrm = (float*)alloc((size_t)E * 4);
  float* t12 = (float*)alloc((size_t)N * 128 * 4);  // GEMM1/2 out; reused as GEMM3 out (t3)
  float* H   = (float*)alloc((size_t)N * 128 * 4);  // h1 || h2
  float* t3  = t12;                                  // t12 dead by conv3
  float* out = (float*)d_out;

  // graph normalization (shared by all convs)
  k_set1<<<(N + 255) / 256, 256, 0, stream>>>(dis, N);              // deg = 1 (self-loop)
  k_deg<<<(E + 255) / 256, 256, 0, stream>>>(dst, ea, dis, E);      // deg += ew at dst
  k_rsqrt<<<(N + 255) / 256, 256, 0, stream>>>(dis, N);             // dis = deg^-1/2
  k_norm<<<(E + 255) / 256, 256, 0, stream>>>(src, dst, ea, dis, nrm, E);

  dim3 g64((N + 63) / 64, 1);
  dim3 g128((N + 63) / 64, 2);
  const int tot64 = N * 64;
  const int tot128 = N * 128;

  // conv1: t1 = x @ W1 ; h1 = scatter + self + b1 -> H[:,0:64]
  k_gemm<<<g64, 256, 0, stream>>>(x, 512, W1, 64, t12, 64, N, 512);
  k_agg_init<6><<<(tot64 + 255) / 256, 256, 0, stream>>>(t12, dis, b1, H, 128, 0, tot64);
  k_agg_edges<6><<<(E + 3) / 4, 256, 0, stream>>>(t12, src, dst, nrm, H, 128, 0, E);

  // conv2: t2 = h1 @ W2 ; h2 -> H[:,64:128]
  k_gemm<<<g64, 256, 0, stream>>>(H, 128, W2, 64, t12, 64, N, 64);
  k_agg_init<6><<<(tot64 + 255) / 256, 256, 0, stream>>>(t12, dis, b2, H, 128, 64, tot64);
  k_agg_edges<6><<<(E + 3) / 4, 256, 0, stream>>>(t12, src, dst, nrm, H, 128, 64, E);

  // conv3: t3 = [h1,h2] @ W3 ; h3 -> d_out
  k_gemm<<<g128, 256, 0, stream>>>(H, 128, W3, 128, t3, 128, N, 128);
  k_agg_init<7><<<(tot128 + 255) / 256, 256, 0, stream>>>(t3, dis, b3, out, 128, 0, tot128);
  k_agg_edges<7><<<(E + 1) / 2, 256, 0, stream>>>(t3, src, dst, nrm, out, 128, 0, E);

  // softmax rows
  k_softmax128<<<(N + 3) / 4, 256, 0, stream>>>(out, N);
}

// Round 3
// 460.393 us; speedup vs baseline: 1.9708x; 1.9708x over previous
//
#include <hip/hip_runtime.h>
#include <cstdint>
#include <cstddef>

#define NN 50000

// ---------------- small utility kernels ----------------

__global__ __launch_bounds__(256) void k_set1(float* __restrict__ p, int n) {
  int i = blockIdx.x * 256 + threadIdx.x;
  if (i < n) p[i] = 1.0f;
}

__global__ __launch_bounds__(256) void k_zero_int(int* __restrict__ p, int n) {
  int i = blockIdx.x * 256 + threadIdx.x;
  if (i < n) p[i] = 0;
}

__global__ void k_seti(int* __restrict__ p, int v) { *p = v; }

// deg[dst] += ew  and  cnt[dst] += 1
__global__ __launch_bounds__(256) void k_deg_hist(const int* __restrict__ dst,
                                                  const float* __restrict__ ew,
                                                  float* __restrict__ deg,
                                                  int* __restrict__ cnt, int E) {
  int e = blockIdx.x * 256 + threadIdx.x;
  if (e < E) {
    int d = dst[e];
    atomicAdd(&deg[d], ew[e]);
    atomicAdd(&cnt[d], 1);
  }
}

__global__ __launch_bounds__(256) void k_rsqrt(float* __restrict__ p, int n) {
  int i = blockIdx.x * 256 + threadIdx.x;
  if (i < n) p[i] = rsqrtf(p[i]);
}

// ---------------- exclusive scan over int[n] (1024 elems / block) ----------------

__global__ __launch_bounds__(256) void k_scan1(const int* __restrict__ in,
                                               int* __restrict__ out,
                                               int* __restrict__ bsum, int n) {
  __shared__ int ts[256];
  int base = blockIdx.x * 1024 + threadIdx.x * 4;
  int v[4] = {0, 0, 0, 0};
#pragma unroll
  for (int j = 0; j < 4; ++j) { int i = base + j; if (i < n) v[j] = in[i]; }
  int s = v[0] + v[1] + v[2] + v[3];
  ts[threadIdx.x] = s;
  __syncthreads();
  for (int o = 1; o < 256; o <<= 1) {
    int t = (threadIdx.x >= o) ? ts[threadIdx.x - o] : 0;
    __syncthreads();
    ts[threadIdx.x] += t;
    __syncthreads();
  }
  int run = ts[threadIdx.x] - s;  // exclusive prefix of this thread's chunk
#pragma unroll
  for (int j = 0; j < 4; ++j) { int i = base + j; if (i < n) out[i] = run; run += v[j]; }
  if (threadIdx.x == 255) bsum[blockIdx.x] = ts[255];
}

__global__ void k_scan2(int* __restrict__ bsum, int nb) {
  if (threadIdx.x == 0) {
    int run = 0;
    for (int b = 0; b < nb; ++b) { int t = bsum[b]; bsum[b] = run; run += t; }
  }
}

__global__ __launch_bounds__(256) void k_scan3(int* __restrict__ out,
                                               const int* __restrict__ bsum, int n) {
  int i = blockIdx.x * 256 + threadIdx.x;
  if (i < n) out[i] += bsum[i >> 10];
}

// ---------------- edge scatter into dst-sorted order ----------------
// src_s[pos] = src[e]; nrm_s[pos] = dis[src]*ew*dis[dst]

__global__ __launch_bounds__(256) void k_scatter(const int* __restrict__ src,
                                                 const int* __restrict__ dst,
                                                 const float* __restrict__ ew,
                                                 const float* __restrict__ dis,
                                                 const int* __restrict__ row_ptr,
                                                 int* __restrict__ cursor,
                                                 int* __restrict__ src_s,
                                                 float* __restrict__ nrm_s, int E) {
  int e = blockIdx.x * 256 + threadIdx.x;
  if (e >= E) return;
  int d = dst[e];
  int s = src[e];
  int pos = row_ptr[d] + atomicAdd(&cursor[d], 1);
  src_s[pos] = s;
  nrm_s[pos] = dis[s] * ew[e] * dis[d];
}

// ---------------- fp32 tiled GEMM: C[N,F] = A[N,K] @ B[K,F] ----------------

__global__ __launch_bounds__(256) void k_gemm(const float* __restrict__ A, int lda,
                                              const float* __restrict__ B, int ldb,
                                              float* __restrict__ C, int ldc,
                                              int N, int K) {
  __shared__ float As[64][68];  // [k][m], padded
  __shared__ float Bs[64][68];  // [k][n]
  const int tid = threadIdx.x;
  const int bm = blockIdx.x * 64;
  const int bn = blockIdx.y * 64;
  const int tx = tid & 15;
  const int ty = tid >> 4;
  float acc[4][4] = {};

  for (int kt = 0; kt < K; kt += 64) {
#pragma unroll
    for (int p = 0; p < 4; ++p) {
      int s = tid + p * 256;
      int r = s >> 4;
      int c4 = (s & 15) << 2;
      float4 va = make_float4(0.f, 0.f, 0.f, 0.f);
      int gr = bm + r;
      if (gr < N) va = *(const float4*)(A + (size_t)gr * lda + kt + c4);
      As[c4 + 0][r] = va.x;
      As[c4 + 1][r] = va.y;
      As[c4 + 2][r] = va.z;
      As[c4 + 3][r] = va.w;
      float4 vb = *(const float4*)(B + (size_t)(kt + r) * ldb + bn + c4);
      *(float4*)(&Bs[r][c4]) = vb;
    }
    __syncthreads();
#pragma unroll
    for (int kk = 0; kk < 64; ++kk) {
      float4 a4 = *(const float4*)(&As[kk][ty * 4]);
      float4 b4 = *(const float4*)(&Bs[kk][tx * 4]);
      float a[4] = {a4.x, a4.y, a4.z, a4.w};
      float b[4] = {b4.x, b4.y, b4.z, b4.w};
#pragma unroll
      for (int i = 0; i < 4; ++i)
#pragma unroll
        for (int j = 0; j < 4; ++j) acc[i][j] += a[i] * b[j];
    }
    __syncthreads();
  }

#pragma unroll
  for (int i = 0; i < 4; ++i) {
    int gr = bm + ty * 4 + i;
    if (gr < N) {
      float4 v = make_float4(acc[i][0], acc[i][1], acc[i][2], acc[i][3]);
      *(float4*)(C + (size_t)gr * ldc + bn + tx * 4) = v;
    }
  }
}

// ---------------- gather aggregation (CSR path) ----------------
// out[n, coloff+f] = bias[f] + dis[n]^2 * t[n,f] + sum_i nrm_s[i] * t[src_s[i], f]

template <int LOGF>
__global__ __launch_bounds__(256) void k_gather(const float* __restrict__ t,
                                                const int* __restrict__ row_ptr,
                                                const int* __restrict__ src_s,
                                                const float* __restrict__ nrm_s,
                                                const float* __restrict__ dis,
                                                const float* __restrict__ bias,
                                                float* __restrict__ out, int ldo,
                                                int coloff, int N) {
  constexpr int F = 1 << LOGF;
  int node = blockIdx.x * (256 >> LOGF) + (threadIdx.x >> LOGF);
  if (node >= N) return;
  int f = threadIdx.x & (F - 1);
  float d = dis[node];
  float acc0 = bias[f] + d * d * t[(size_t)node * F + f];
  float acc1 = 0.f;
  int beg = row_ptr[node], end = row_ptr[node + 1];
  int i = beg;
  for (; i + 1 < end; i += 2) {
    int s0 = src_s[i], s1 = src_s[i + 1];
    float w0 = nrm_s[i], w1 = nrm_s[i + 1];
    acc0 += w0 * t[(size_t)s0 * F + f];
    acc1 += w1 * t[(size_t)s1 * F + f];
  }
  if (i < end) acc0 += nrm_s[i] * t[(size_t)src_s[i] * F + f];
  out[(size_t)node * ldo + coloff + f] = acc0 + acc1;
}

// ---------------- atomic fallback (round-1 path, used only if ws too small) ----

template <int LOGF>
__global__ __launch_bounds__(256) void k_agg_init(const float* __restrict__ t,
                                                  const float* __restrict__ dis,
                                                  const float* __restrict__ bias,
                                                  float* __restrict__ out, int ldo,
                                                  int coloff, int n_total) {
  int idx = blockIdx.x * 256 + threadIdx.x;
  if (idx >= n_total) return;
  int n = idx >> LOGF;
  int f = idx & ((1 << LOGF) - 1);
  float d = dis[n];
  out[(size_t)n * ldo + coloff + f] = bias[f] + d * d * t[idx];
}

template <int LOGF>
__global__ __launch_bounds__(256) void k_agg_edges(const float* __restrict__ t,
                                                   const int* __restrict__ src,
                                                   const int* __restrict__ dst,
                                                   const float* __restrict__ nrm,
                                                   float* __restrict__ out, int ldo,
                                                   int coloff, int E) {
  constexpr int F = 1 << LOGF;
  constexpr int EPB = 256 >> LOGF;
  int e = blockIdx.x * EPB + (threadIdx.x >> LOGF);
  if (e >= E) return;
  int f = threadIdx.x & (F - 1);
  int s = src[e];
  int d = dst[e];
  float v = nrm[e] * t[(size_t)s * F + f];
  atomicAdd(&out[(size_t)d * ldo + coloff + f], v);
}

__global__ __launch_bounds__(256) void k_norm(const int* __restrict__ src,
                                              const int* __restrict__ dst,
                                              const float* __restrict__ ew,
                                              const float* __restrict__ dis,
                                              float* __restrict__ nrm, int E) {
  int e = blockIdx.x * 256 + threadIdx.x;
  if (e < E) nrm[e] = dis[src[e]] * ew[e] * dis[dst[e]];
}

// ---------------- row softmax over 128 cols, one wave per row ----------------
__global__ __launch_bounds__(256) void k_softmax128(float* __restrict__ h, int N) {
  int row = blockIdx.x * 4 + (threadIdx.x >> 6);
  if (row >= N) return;
  int lane = threadIdx.x & 63;
  float* p = h + (size_t)row * 128;
  float v0 = p[lane];
  float v1 = p[lane + 64];
  float m = fmaxf(v0, v1);
#pragma unroll
  for (int o = 32; o > 0; o >>= 1) m = fmaxf(m, __shfl_xor(m, o));
  float e0 = __expf(v0 - m);
  float e1 = __expf(v1 - m);
  float sum = e0 + e1;
#pragma unroll
  for (int o = 32; o > 0; o >>= 1) sum += __shfl_xor(sum, o);
  float inv = 1.0f / sum;
  p[lane] = e0 * inv;
  p[lane + 64] = e1 * inv;
}

// ---------------- launch ----------------
extern "C" void kernel_launch(void* const* d_in, const int* in_sizes, int n_in,
                              void* d_out, int out_size, void* d_ws, size_t ws_size,
                              hipStream_t stream) {
  const float* x = (const float*)d_in[0];
  const int* ei = (const int*)d_in[1];  // integer inputs arrive as int32
  const float* ea = (const float*)d_in[2];
  const float* W1 = (const float*)d_in[3];
  const float* b1 = (const float*)d_in[4];
  const float* W2 = (const float*)d_in[5];
  const float* b2 = (const float*)d_in[6];
  const float* W3 = (const float*)d_in[7];
  const float* b3 = (const float*)d_in[8];

  const int N = NN;
  const int E = in_sizes[2];
  const int* src = ei;
  const int* dst = ei + E;

  char* ws = (char*)d_ws;
  size_t off = 0;
  auto alloc = [&](size_t bytes) {
    void* p = (void*)(ws + off);
    off += (bytes + 255) & ~(size_t)255;
    return p;
  };

  // common
  float* dis = (float*)alloc((size_t)N * 4);
  // sort-path buffers
  int* row_ptr = (int*)alloc((size_t)(N + 1) * 4);
  int* cnt = (int*)alloc((size_t)N * 4);       // histogram, then reused as scatter cursor
  int* bsum = (int*)alloc(256 * 4);            // scan block sums
  int* src_s = (int*)alloc((size_t)E * 4);
  float* nrm_s = (float*)alloc((size_t)E * 4);
  size_t sort_off = off;
  // dense buffers (both paths)
  float* t12 = (float*)(ws + sort_off);                      // [N,128] gemm out
  float* H = (float*)(ws + sort_off + (size_t)N * 128 * 4 + 256);  // [N,128] h1||h2
  size_t need_sort = sort_off + 2 * ((size_t)N * 128 * 4 + 256);
  float* out = (float*)d_out;

  const bool useSort = (ws_size >= need_sort);

  dim3 g64((N + 63) / 64, 1);
  dim3 g128((N + 63) / 64, 2);
  const int tot64 = N * 64;
  const int tot128 = N * 128;
  const int NB_SCAN = (N + 1023) / 1024;

  if (useSort) {
    // ---- graph preprocessing: degrees + CSR by dst ----
    k_set1<<<(N + 255) / 256, 256, 0, stream>>>(dis, N);  // deg starts at 1 (self-loop)
    k_zero_int<<<(N + 255) / 256, 256, 0, stream>>>(cnt, N);
    k_deg_hist<<<(E + 255) / 256, 256, 0, stream>>>(dst, ea, dis, cnt, E);
    k_rsqrt<<<(N + 255) / 256, 256, 0, stream>>>(dis, N);
    k_scan1<<<NB_SCAN, 256, 0, stream>>>(cnt, row_ptr, bsum, N);
    k_scan2<<<1, 64, 0, stream>>>(bsum, NB_SCAN);
    k_scan3<<<(N + 255) / 256, 256, 0, stream>>>(row_ptr, bsum, N);
    k_seti<<<1, 1, 0, stream>>>(row_ptr + N, E);
    k_zero_int<<<(N + 255) / 256, 256, 0, stream>>>(cnt, N);  // cursor
    k_scatter<<<(E + 255) / 256, 256, 0, stream>>>(src, dst, ea, dis, row_ptr, cnt,
                                                   src_s, nrm_s, E);

    // conv1: t1 = x @ W1 ; h1 -> H[:,0:64]
    k_gemm<<<g64, 256, 0, stream>>>(x, 512, W1, 64, t12, 64, N, 512);
    k_gather<6><<<(N + 3) / 4, 256, 0, stream>>>(t12, row_ptr, src_s, nrm_s, dis, b1,
                                                 H, 128, 0, N);
    // conv2: t2 = h1 @ W2 ; h2 -> H[:,64:128]
    k_gemm<<<g64, 256, 0, stream>>>(H, 128, W2, 64, t12, 64, N, 64);
    k_gather<6><<<(N + 3) / 4, 256, 0, stream>>>(t12, row_ptr, src_s, nrm_s, dis, b2,
                                                 H, 128, 64, N);
    // conv3: t3 = [h1,h2] @ W3 ; h3 -> d_out
    k_gemm<<<g128, 256, 0, stream>>>(H, 128, W3, 128, t12, 128, N, 128);
    k_gather<7><<<(N + 1) / 2, 256, 0, stream>>>(t12, row_ptr, src_s, nrm_s, dis, b3,
                                                 out, 128, 0, N);
  } else {
    // ---- fallback: round-1 atomic path (proven to fit) ----
    off = 0;
    dis = (float*)alloc((size_t)N * 4);
    float* nrm = (float*)alloc((size_t)E * 4);
    t12 = (float*)alloc((size_t)N * 128 * 4);
    H = (float*)alloc((size_t)N * 128 * 4);

    k_set1<<<(N + 255) / 256, 256, 0, stream>>>(dis, N);
    k_deg_hist<<<(E + 255) / 256, 256, 0, stream>>>(dst, ea, dis, nullptr, 0);  // no-op
    {
      // degree accumulate without histogram
      k_norm<<<1, 1, 0, stream>>>(src, dst, ea, dis, nrm, 0);  // no-op placeholder
    }
    // (plain degree pass)
    // reuse k_deg_hist pattern via dedicated launches:
    // deg
    // NOTE: simple sequence identical to round 1
    k_set1<<<(N + 255) / 256, 256, 0, stream>>>(dis, N);
    // deg += ew at dst
    // use k_agg-style atomic kernel:
    // (small dedicated kernel)
    struct L {};  // no-op
    // fall back to lambda-free explicit kernels:
    extern __global__ void k_deg_only(const int*, const float*, float*, int);
    k_deg_only<<<(E + 255) / 256, 256, 0, stream>>>(dst, ea, dis, E);
    k_rsqrt<<<(N + 255) / 256, 256, 0, stream>>>(dis, N);
    k_norm<<<(E + 255) / 256, 256, 0, stream>>>(src, dst, ea, dis, nrm, E);

    k_gemm<<<g64, 256, 0, stream>>>(x, 512, W1, 64, t12, 64, N, 512);
    k_agg_init<6><<<(tot64 + 255) / 256, 256, 0, stream>>>(t12, dis, b1, H, 128, 0, tot64);
    k_agg_edges<6><<<(E + 3) / 4, 256, 0, stream>>>(t12, src, dst, nrm, H, 128, 0, E);

    k_gemm<<<g64, 256, 0, stream>>>(H, 128, W2, 64, t12, 64, N, 64);
    k_agg_init<6><<<(tot64 + 255) / 256, 256, 0, stream>>>(t12, dis, b2, H, 128, 64, tot64);
    k_agg_edges<6><<<(E + 3) / 4, 256, 0, stream>>>(t12, src, dst, nrm, H, 128, 64, E);

    k_gemm<<<g128, 256, 0, stream>>>(H, 128, W3, 128, t12, 128, N, 128);
    k_agg_init<7><<<(tot128 + 255) / 256, 256, 0, stream>>>(t12, dis, b3, out, 128, 0, tot128);
    k_agg_edges<7><<<(E + 1) / 2, 256, 0, stream>>>(t12, src, dst, nrm, out, 128, 0, E);
  }

  k_softmax128<<<(N + 3) / 4, 256, 0, stream>>>(out, N);
}

// fallback-only degree kernel
__global__ __launch_bounds__(256) void k_deg_only(const int* __restrict__ dst,
                                                  const float* __restrict__ ew,
                                                  float* __restrict__ deg, int E) {
  int e = blockIdx.x * 256 + threadIdx.x;
  if (e < E) atomicAdd(&deg[dst[e]], ew[e]);
}

// Round 4
// 371.467 us; speedup vs baseline: 2.4426x; 1.2394x over previous
//
#include <hip/hip_runtime.h>
#include <cstdint>
#include <cstddef>

#define NN 50000

// ---------------- small utility kernels ----------------

__global__ __launch_bounds__(256) void k_init(float* __restrict__ deg,
                                              int* __restrict__ cnt, int n) {
  int i = blockIdx.x * 256 + threadIdx.x;
  if (i < n) { deg[i] = 1.0f; cnt[i] = 0; }
}

__global__ __launch_bounds__(256) void k_zero_int(int* __restrict__ p, int n) {
  int i = blockIdx.x * 256 + threadIdx.x;
  if (i < n) p[i] = 0;
}

__global__ void k_seti(int* __restrict__ p, int v) { *p = v; }

// deg[dst] += ew  and  cnt[dst] += 1
__global__ __launch_bounds__(256) void k_deg_hist(const int* __restrict__ dst,
                                                  const float* __restrict__ ew,
                                                  float* __restrict__ deg,
                                                  int* __restrict__ cnt, int E) {
  int e = blockIdx.x * 256 + threadIdx.x;
  if (e < E) {
    int d = dst[e];
    atomicAdd(&deg[d], ew[e]);
    atomicAdd(&cnt[d], 1);
  }
}

__global__ __launch_bounds__(256) void k_rsqrt(float* __restrict__ p, int n) {
  int i = blockIdx.x * 256 + threadIdx.x;
  if (i < n) p[i] = rsqrtf(p[i]);
}

// ---------------- exclusive scan over int[n] (1024 elems / block) ----------------

__global__ __launch_bounds__(256) void k_scan1(const int* __restrict__ in,
                                               int* __restrict__ out,
                                               int* __restrict__ bsum, int n) {
  __shared__ int ts[256];
  int base = blockIdx.x * 1024 + threadIdx.x * 4;
  int v[4] = {0, 0, 0, 0};
#pragma unroll
  for (int j = 0; j < 4; ++j) { int i = base + j; if (i < n) v[j] = in[i]; }
  int s = v[0] + v[1] + v[2] + v[3];
  ts[threadIdx.x] = s;
  __syncthreads();
  for (int o = 1; o < 256; o <<= 1) {
    int t = (threadIdx.x >= o) ? ts[threadIdx.x - o] : 0;
    __syncthreads();
    ts[threadIdx.x] += t;
    __syncthreads();
  }
  int run = ts[threadIdx.x] - s;
#pragma unroll
  for (int j = 0; j < 4; ++j) { int i = base + j; if (i < n) out[i] = run; run += v[j]; }
  if (threadIdx.x == 255) bsum[blockIdx.x] = ts[255];
}

__global__ void k_scan2(int* __restrict__ bsum, int nb) {
  if (threadIdx.x == 0) {
    int run = 0;
    for (int b = 0; b < nb; ++b) { int t = bsum[b]; bsum[b] = run; run += t; }
  }
}

__global__ __launch_bounds__(256) void k_scan3(int* __restrict__ out,
                                               const int* __restrict__ bsum, int n) {
  int i = blockIdx.x * 256 + threadIdx.x;
  if (i < n) out[i] += bsum[i >> 10];
}

// ---------------- edge scatter into dst-sorted order ----------------
// edge_s[pos] = { src[e], bits(dis[src]*ew*dis[dst]) }

__global__ __launch_bounds__(256) void k_scatter(const int* __restrict__ src,
                                                 const int* __restrict__ dst,
                                                 const float* __restrict__ ew,
                                                 const float* __restrict__ dis,
                                                 const int* __restrict__ row_ptr,
                                                 int* __restrict__ cursor,
                                                 int2* __restrict__ edge_s, int E) {
  int e = blockIdx.x * 256 + threadIdx.x;
  if (e >= E) return;
  int d = dst[e];
  int s = src[e];
  int pos = row_ptr[d] + atomicAdd(&cursor[d], 1);
  float w = dis[s] * ew[e] * dis[d];
  edge_s[pos] = make_int2(s, __float_as_int(w));
}

// ---------------- fp32 tiled GEMM: C[N,F] = A[N,K] @ B[K,F] ----------------

__global__ __launch_bounds__(256) void k_gemm(const float* __restrict__ A, int lda,
                                              const float* __restrict__ B, int ldb,
                                              float* __restrict__ C, int ldc,
                                              int N, int K) {
  __shared__ float As[64][68];
  __shared__ float Bs[64][68];
  const int tid = threadIdx.x;
  const int bm = blockIdx.x * 64;
  const int bn = blockIdx.y * 64;
  const int tx = tid & 15;
  const int ty = tid >> 4;
  float acc[4][4] = {};

  for (int kt = 0; kt < K; kt += 64) {
#pragma unroll
    for (int p = 0; p < 4; ++p) {
      int s = tid + p * 256;
      int r = s >> 4;
      int c4 = (s & 15) << 2;
      float4 va = make_float4(0.f, 0.f, 0.f, 0.f);
      int gr = bm + r;
      if (gr < N) va = *(const float4*)(A + (size_t)gr * lda + kt + c4);
      As[c4 + 0][r] = va.x;
      As[c4 + 1][r] = va.y;
      As[c4 + 2][r] = va.z;
      As[c4 + 3][r] = va.w;
      float4 vb = *(const float4*)(B + (size_t)(kt + r) * ldb + bn + c4);
      *(float4*)(&Bs[r][c4]) = vb;
    }
    __syncthreads();
#pragma unroll
    for (int kk = 0; kk < 64; ++kk) {
      float4 a4 = *(const float4*)(&As[kk][ty * 4]);
      float4 b4 = *(const float4*)(&Bs[kk][tx * 4]);
      float a[4] = {a4.x, a4.y, a4.z, a4.w};
      float b[4] = {b4.x, b4.y, b4.z, b4.w};
#pragma unroll
      for (int i = 0; i < 4; ++i)
#pragma unroll
        for (int j = 0; j < 4; ++j) acc[i][j] += a[i] * b[j];
    }
    __syncthreads();
  }

#pragma unroll
  for (int i = 0; i < 4; ++i) {
    int gr = bm + ty * 4 + i;
    if (gr < N) {
      float4 v = make_float4(acc[i][0], acc[i][1], acc[i][2], acc[i][3]);
      *(float4*)(C + (size_t)gr * ldc + bn + tx * 4) = v;
    }
  }
}

// ---------------- gather aggregation (CSR, float4/thread, unroll 4) ----------------
// out[n, coloff+f] = bias[f] + dis[n]^2 * t[n,f] + sum_i w_i * t[s_i, f]
// F/4 threads per node; optionally fuse row softmax (F=128: 32 lanes hold the row).

template <int LOGF, bool SMAX>
__global__ __launch_bounds__(256) void k_gather4(const float* __restrict__ t,
                                                 const int* __restrict__ row_ptr,
                                                 const int2* __restrict__ edge_s,
                                                 const float* __restrict__ dis,
                                                 const float* __restrict__ bias,
                                                 float* __restrict__ out, int ldo,
                                                 int coloff, int N) {
  constexpr int F = 1 << LOGF;
  constexpr int TPN = F / 4;  // threads per node
  int node = blockIdx.x * (256 / TPN) + threadIdx.x / TPN;
  if (node >= N) return;
  int f4 = (threadIdx.x % TPN) * 4;

  const float4 bv = *(const float4*)(bias + f4);
  const float dn = dis[node];
  const float dd = dn * dn;
  const float4 tv = *(const float4*)(t + (size_t)node * F + f4);
  float4 a0, a1;
  a0.x = bv.x + dd * tv.x; a0.y = bv.y + dd * tv.y;
  a0.z = bv.z + dd * tv.z; a0.w = bv.w + dd * tv.w;
  a1.x = a1.y = a1.z = a1.w = 0.f;

  const int beg = row_ptr[node], end = row_ptr[node + 1];
  int i = beg;
  for (; i + 4 <= end; i += 4) {
    int2 e0 = edge_s[i], e1 = edge_s[i + 1], e2 = edge_s[i + 2], e3 = edge_s[i + 3];
    float w0 = __int_as_float(e0.y), w1 = __int_as_float(e1.y);
    float w2 = __int_as_float(e2.y), w3 = __int_as_float(e3.y);
    float4 v0 = *(const float4*)(t + (size_t)e0.x * F + f4);
    float4 v1 = *(const float4*)(t + (size_t)e1.x * F + f4);
    float4 v2 = *(const float4*)(t + (size_t)e2.x * F + f4);
    float4 v3 = *(const float4*)(t + (size_t)e3.x * F + f4);
    a0.x += w0 * v0.x; a0.y += w0 * v0.y; a0.z += w0 * v0.z; a0.w += w0 * v0.w;
    a1.x += w1 * v1.x; a1.y += w1 * v1.y; a1.z += w1 * v1.z; a1.w += w1 * v1.w;
    a0.x += w2 * v2.x; a0.y += w2 * v2.y; a0.z += w2 * v2.z; a0.w += w2 * v2.w;
    a1.x += w3 * v3.x; a1.y += w3 * v3.y; a1.z += w3 * v3.z; a1.w += w3 * v3.w;
  }
  for (; i < end; ++i) {
    int2 e0 = edge_s[i];
    float w0 = __int_as_float(e0.y);
    float4 v0 = *(const float4*)(t + (size_t)e0.x * F + f4);
    a0.x += w0 * v0.x; a0.y += w0 * v0.y; a0.z += w0 * v0.z; a0.w += w0 * v0.w;
  }
  float4 v;
  v.x = a0.x + a1.x; v.y = a0.y + a1.y; v.z = a0.z + a1.z; v.w = a0.w + a1.w;

  if constexpr (SMAX) {
    // softmax across the node's TPN (=32) lanes * 4 values
    float m = fmaxf(fmaxf(v.x, v.y), fmaxf(v.z, v.w));
#pragma unroll
    for (int o = 1; o < TPN; o <<= 1) m = fmaxf(m, __shfl_xor(m, o));
    v.x = __expf(v.x - m); v.y = __expf(v.y - m);
    v.z = __expf(v.z - m); v.w = __expf(v.w - m);
    float s = v.x + v.y + v.z + v.w;
#pragma unroll
    for (int o = 1; o < TPN; o <<= 1) s += __shfl_xor(s, o);
    float inv = 1.0f / s;
    v.x *= inv; v.y *= inv; v.z *= inv; v.w *= inv;
  }
  *(float4*)(out + (size_t)node * ldo + coloff + f4) = v;
}

// ---------------- atomic fallback path (only if ws too small) ----------------

__global__ __launch_bounds__(256) void k_deg_only(const int* __restrict__ dst,
                                                  const float* __restrict__ ew,
                                                  float* __restrict__ deg, int E) {
  int e = blockIdx.x * 256 + threadIdx.x;
  if (e < E) atomicAdd(&deg[dst[e]], ew[e]);
}

__global__ __launch_bounds__(256) void k_set1(float* __restrict__ p, int n) {
  int i = blockIdx.x * 256 + threadIdx.x;
  if (i < n) p[i] = 1.0f;
}

__global__ __launch_bounds__(256) void k_norm(const int* __restrict__ src,
                                              const int* __restrict__ dst,
                                              const float* __restrict__ ew,
                                              const float* __restrict__ dis,
                                              float* __restrict__ nrm, int E) {
  int e = blockIdx.x * 256 + threadIdx.x;
  if (e < E) nrm[e] = dis[src[e]] * ew[e] * dis[dst[e]];
}

template <int LOGF>
__global__ __launch_bounds__(256) void k_agg_init(const float* __restrict__ t,
                                                  const float* __restrict__ dis,
                                                  const float* __restrict__ bias,
                                                  float* __restrict__ out, int ldo,
                                                  int coloff, int n_total) {
  int idx = blockIdx.x * 256 + threadIdx.x;
  if (idx >= n_total) return;
  int n = idx >> LOGF;
  int f = idx & ((1 << LOGF) - 1);
  float d = dis[n];
  out[(size_t)n * ldo + coloff + f] = bias[f] + d * d * t[idx];
}

template <int LOGF>
__global__ __launch_bounds__(256) void k_agg_edges(const float* __restrict__ t,
                                                   const int* __restrict__ src,
                                                   const int* __restrict__ dst,
                                                   const float* __restrict__ nrm,
                                                   float* __restrict__ out, int ldo,
                                                   int coloff, int E) {
  constexpr int F = 1 << LOGF;
  constexpr int EPB = 256 >> LOGF;
  int e = blockIdx.x * EPB + (threadIdx.x >> LOGF);
  if (e >= E) return;
  int f = threadIdx.x & (F - 1);
  int s = src[e];
  int d = dst[e];
  float v = nrm[e] * t[(size_t)s * F + f];
  atomicAdd(&out[(size_t)d * ldo + coloff + f], v);
}

__global__ __launch_bounds__(256) void k_softmax128(float* __restrict__ h, int N) {
  int row = blockIdx.x * 4 + (threadIdx.x >> 6);
  if (row >= N) return;
  int lane = threadIdx.x & 63;
  float* p = h + (size_t)row * 128;
  float v0 = p[lane];
  float v1 = p[lane + 64];
  float m = fmaxf(v0, v1);
#pragma unroll
  for (int o = 32; o > 0; o >>= 1) m = fmaxf(m, __shfl_xor(m, o));
  float e0 = __expf(v0 - m);
  float e1 = __expf(v1 - m);
  float sum = e0 + e1;
#pragma unroll
  for (int o = 32; o > 0; o >>= 1) sum += __shfl_xor(sum, o);
  float inv = 1.0f / sum;
  p[lane] = e0 * inv;
  p[lane + 64] = e1 * inv;
}

// ---------------- launch ----------------
extern "C" void kernel_launch(void* const* d_in, const int* in_sizes, int n_in,
                              void* d_out, int out_size, void* d_ws, size_t ws_size,
                              hipStream_t stream) {
  const float* x = (const float*)d_in[0];
  const int* ei = (const int*)d_in[1];  // integer inputs arrive as int32
  const float* ea = (const float*)d_in[2];
  const float* W1 = (const float*)d_in[3];
  const float* b1 = (const float*)d_in[4];
  const float* W2 = (const float*)d_in[5];
  const float* b2 = (const float*)d_in[6];
  const float* W3 = (const float*)d_in[7];
  const float* b3 = (const float*)d_in[8];

  const int N = NN;
  const int E = in_sizes[2];
  const int* src = ei;
  const int* dst = ei + E;

  char* ws = (char*)d_ws;
  size_t off = 0;
  auto alloc = [&](size_t bytes) {
    void* p = (void*)(ws + off);
    off += (bytes + 255) & ~(size_t)255;
    return p;
  };

  float* dis = (float*)alloc((size_t)N * 4);
  int* row_ptr = (int*)alloc((size_t)(N + 1) * 4);
  int* cnt = (int*)alloc((size_t)N * 4);
  int* bsum = (int*)alloc(256 * 4);
  int2* edge_s = (int2*)alloc((size_t)E * 8);
  float* t12 = (float*)alloc((size_t)N * 128 * 4);
  float* H = (float*)alloc((size_t)N * 128 * 4);
  size_t need_sort = off;
  float* out = (float*)d_out;

  const bool useSort = (ws_size >= need_sort);

  dim3 g64((N + 63) / 64, 1);
  dim3 g128((N + 63) / 64, 2);
  const int NB_SCAN = (N + 1023) / 1024;

  if (useSort) {
    // ---- CSR-by-dst preprocessing ----
    k_init<<<(N + 255) / 256, 256, 0, stream>>>(dis, cnt, N);
    k_deg_hist<<<(E + 255) / 256, 256, 0, stream>>>(dst, ea, dis, cnt, E);
    k_rsqrt<<<(N + 255) / 256, 256, 0, stream>>>(dis, N);
    k_scan1<<<NB_SCAN, 256, 0, stream>>>(cnt, row_ptr, bsum, N);
    k_scan2<<<1, 64, 0, stream>>>(bsum, NB_SCAN);
    k_scan3<<<(N + 255) / 256, 256, 0, stream>>>(row_ptr, bsum, N);
    k_seti<<<1, 1, 0, stream>>>(row_ptr + N, E);
    k_zero_int<<<(N + 255) / 256, 256, 0, stream>>>(cnt, N);
    k_scatter<<<(E + 255) / 256, 256, 0, stream>>>(src, dst, ea, dis, row_ptr, cnt,
                                                   edge_s, E);

    // conv1: t1 = x @ W1 ; h1 -> H[:,0:64]
    k_gemm<<<g64, 256, 0, stream>>>(x, 512, W1, 64, t12, 64, N, 512);
    k_gather4<6, false><<<(N + 15) / 16, 256, 0, stream>>>(t12, row_ptr, edge_s, dis,
                                                           b1, H, 128, 0, N);
    // conv2: t2 = h1 @ W2 ; h2 -> H[:,64:128]
    k_gemm<<<g64, 256, 0, stream>>>(H, 128, W2, 64, t12, 64, N, 64);
    k_gather4<6, false><<<(N + 15) / 16, 256, 0, stream>>>(t12, row_ptr, edge_s, dis,
                                                           b2, H, 128, 64, N);
    // conv3: t3 = [h1,h2] @ W3 ; softmax(A t3 + b3) -> d_out (fused)
    k_gemm<<<g128, 256, 0, stream>>>(H, 128, W3, 128, t12, 128, N, 128);
    k_gather4<7, true><<<(N + 7) / 8, 256, 0, stream>>>(t12, row_ptr, edge_s, dis,
                                                        b3, out, 128, 0, N);
  } else {
    // ---- fallback: atomic scatter path ----
    off = 0;
    dis = (float*)alloc((size_t)N * 4);
    float* nrm = (float*)alloc((size_t)E * 4);
    t12 = (float*)alloc((size_t)N * 128 * 4);
    H = (float*)alloc((size_t)N * 128 * 4);
    const int tot64 = N * 64, tot128 = N * 128;

    k_set1<<<(N + 255) / 256, 256, 0, stream>>>(dis, N);
    k_deg_only<<<(E + 255) / 256, 256, 0, stream>>>(dst, ea, dis, E);
    k_rsqrt<<<(N + 255) / 256, 256, 0, stream>>>(dis, N);
    k_norm<<<(E + 255) / 256, 256, 0, stream>>>(src, dst, ea, dis, nrm, E);

    k_gemm<<<g64, 256, 0, stream>>>(x, 512, W1, 64, t12, 64, N, 512);
    k_agg_init<6><<<(tot64 + 255) / 256, 256, 0, stream>>>(t12, dis, b1, H, 128, 0, tot64);
    k_agg_edges<6><<<(E + 3) / 4, 256, 0, stream>>>(t12, src, dst, nrm, H, 128, 0, E);

    k_gemm<<<g64, 256, 0, stream>>>(H, 128, W2, 64, t12, 64, N, 64);
    k_agg_init<6><<<(tot64 + 255) / 256, 256, 0, stream>>>(t12, dis, b2, H, 128, 64, tot64);
    k_agg_edges<6><<<(E + 3) / 4, 256, 0, stream>>>(t12, src, dst, nrm, H, 128, 64, E);

    k_gemm<<<g128, 256, 0, stream>>>(H, 128, W3, 128, t12, 128, N, 128);
    k_agg_init<7><<<(tot128 + 255) / 256, 256, 0, stream>>>(t12, dis, b3, out, 128, 0, tot128);
    k_agg_edges<7><<<(E + 1) / 2, 256, 0, stream>>>(t12, src, dst, nrm, out, 128, 0, E);

    k_softmax128<<<(N + 3) / 4, 256, 0, stream>>>(out, N);
  }
}

// Round 5
// 313.657 us; speedup vs baseline: 2.8928x; 1.1843x over previous
//
#include <hip/hip_runtime.h>
#include <cstdint>
#include <cstddef>

#define NN 50000

typedef __attribute__((ext_vector_type(8))) short short8;
typedef __attribute__((ext_vector_type(4))) float f32x4;

__device__ inline ushort bf16_rne(float x) {
  uint u = __float_as_uint(x);
  uint r = u + 0x7FFFu + ((u >> 16) & 1u);
  return (ushort)(r >> 16);
}
__device__ inline float bf16_to_f(ushort h) { return __uint_as_float(((uint)h) << 16); }

// ---------------- small utility kernels ----------------

__global__ __launch_bounds__(256) void k_init(float* __restrict__ deg,
                                              int* __restrict__ cnt, int n) {
  int i = blockIdx.x * 256 + threadIdx.x;
  if (i < n) { deg[i] = 1.0f; cnt[i] = 0; }
}

__global__ __launch_bounds__(256) void k_zero_int(int* __restrict__ p, int n) {
  int i = blockIdx.x * 256 + threadIdx.x;
  if (i < n) p[i] = 0;
}

__global__ void k_seti(int* __restrict__ p, int v) { *p = v; }

__global__ __launch_bounds__(256) void k_deg_hist(const int* __restrict__ dst,
                                                  const float* __restrict__ ew,
                                                  float* __restrict__ deg,
                                                  int* __restrict__ cnt, int E) {
  int e = blockIdx.x * 256 + threadIdx.x;
  if (e < E) {
    int d = dst[e];
    atomicAdd(&deg[d], ew[e]);
    atomicAdd(&cnt[d], 1);
  }
}

__global__ __launch_bounds__(256) void k_rsqrt(float* __restrict__ p, int n) {
  int i = blockIdx.x * 256 + threadIdx.x;
  if (i < n) p[i] = rsqrtf(p[i]);
}

// W[k][n] fp32  ->  WT_hi[n][k], WT_lo[n][k] bf16 (split)
__global__ __launch_bounds__(256) void k_wsplit(const float* __restrict__ W, int logF,
                                                int K, ushort* __restrict__ th,
                                                ushort* __restrict__ tl, int total) {
  int idx = blockIdx.x * 256 + threadIdx.x;
  if (idx >= total) return;
  int k = idx >> logF;
  int n = idx & ((1 << logF) - 1);
  float w = W[idx];
  ushort h = bf16_rne(w);
  float lof = w - bf16_to_f(h);
  ushort l = bf16_rne(lof);
  th[(size_t)n * K + k] = h;
  tl[(size_t)n * K + k] = l;
}

// ---------------- exclusive scan over int[n] (1024 elems / block) ----------------

__global__ __launch_bounds__(256) void k_scan1(const int* __restrict__ in,
                                               int* __restrict__ out,
                                               int* __restrict__ bsum, int n) {
  __shared__ int ts[256];
  int base = blockIdx.x * 1024 + threadIdx.x * 4;
  int v[4] = {0, 0, 0, 0};
#pragma unroll
  for (int j = 0; j < 4; ++j) { int i = base + j; if (i < n) v[j] = in[i]; }
  int s = v[0] + v[1] + v[2] + v[3];
  ts[threadIdx.x] = s;
  __syncthreads();
  for (int o = 1; o < 256; o <<= 1) {
    int t = (threadIdx.x >= o) ? ts[threadIdx.x - o] : 0;
    __syncthreads();
    ts[threadIdx.x] += t;
    __syncthreads();
  }
  int run = ts[threadIdx.x] - s;
#pragma unroll
  for (int j = 0; j < 4; ++j) { int i = base + j; if (i < n) out[i] = run; run += v[j]; }
  if (threadIdx.x == 255) bsum[blockIdx.x] = ts[255];
}

__global__ void k_scan2(int* __restrict__ bsum, int nb) {
  if (threadIdx.x == 0) {
    int run = 0;
    for (int b = 0; b < nb; ++b) { int t = bsum[b]; bsum[b] = run; run += t; }
  }
}

__global__ __launch_bounds__(256) void k_scan3(int* __restrict__ out,
                                               const int* __restrict__ bsum, int n) {
  int i = blockIdx.x * 256 + threadIdx.x;
  if (i < n) out[i] += bsum[i >> 10];
}

// ---------------- edge scatter into dst-sorted order ----------------

__global__ __launch_bounds__(256) void k_scatter(const int* __restrict__ src,
                                                 const int* __restrict__ dst,
                                                 const float* __restrict__ ew,
                                                 const float* __restrict__ dis,
                                                 const int* __restrict__ row_ptr,
                                                 int* __restrict__ cursor,
                                                 int2* __restrict__ edge_s, int E) {
  int e = blockIdx.x * 256 + threadIdx.x;
  if (e >= E) return;
  int d = dst[e];
  int s = src[e];
  int pos = row_ptr[d] + atomicAdd(&cursor[d], 1);
  float w = dis[s] * ew[e] * dis[d];
  edge_s[pos] = make_int2(s, __float_as_int(w));
}

// ---------------- split-bf16 MFMA GEMM: C[N,BN] = A[N,K] @ B[K,BN] ----------------
// B pre-split+transposed (BTh/BTl, [BN][K] bf16). BM=64, BK=64, 256 threads (4 waves).
// Wave (wm,wn) computes rows [wm*32,+32) x cols [wn*BN/2,+BN/2) as 2 x NT 16x16 tiles.
// LDS row-major [row][64] bf16, XOR swizzle byte^=((row&7)<<4) on store AND read (G4:
// 128B row stride would otherwise be a 32-way bank conflict on ds_read_b128).
// Split product: C = ah*bh + ah*bl + al*bh (fp32 MFMA accum; lo*lo dropped, ~2^-16 rel).

template <int BN>
__global__ __launch_bounds__(256) void k_gemm_mfma(const float* __restrict__ A, int lda,
                                                   const ushort* __restrict__ BTh,
                                                   const ushort* __restrict__ BTl,
                                                   float* __restrict__ C, int ldc,
                                                   int N, int K) {
  constexpr int WN = BN / 2;   // cols per wave
  constexpr int NT = WN / 16;  // 16-col tiles per wave
  __shared__ __align__(16) ushort Ah[64 * 64];
  __shared__ __align__(16) ushort Al[64 * 64];
  __shared__ __align__(16) ushort Bh[BN * 64];
  __shared__ __align__(16) ushort Bl[BN * 64];

  const int tid = threadIdx.x;
  const int lane = tid & 63;
  const int wid = tid >> 6;
  const int wm = wid >> 1;
  const int wn = wid & 1;
  const int bm = blockIdx.x * 64;
  const int l15 = lane & 15;
  const int kgrp = (lane >> 4) << 4;  // byte offset of this lane's 8-elem k-chunk

  f32x4 acc[2][NT] = {};

  for (int kt = 0; kt < K; kt += 64) {
    // ---- stage A: 64x64 fp32 -> bf16 hi/lo in LDS ----
#pragma unroll
    for (int p = 0; p < 4; ++p) {
      int s = tid + p * 256;
      int m = s >> 4;
      int k4 = (s & 15) << 2;
      int gr = bm + m;
      float4 v = make_float4(0.f, 0.f, 0.f, 0.f);
      if (gr < N) v = *(const float4*)(A + (size_t)gr * lda + kt + k4);
      ushort4 h, l;
      h.x = bf16_rne(v.x); l.x = bf16_rne(v.x - bf16_to_f(h.x));
      h.y = bf16_rne(v.y); l.y = bf16_rne(v.y - bf16_to_f(h.y));
      h.z = bf16_rne(v.z); l.z = bf16_rne(v.z - bf16_to_f(h.z));
      h.w = bf16_rne(v.w); l.w = bf16_rne(v.w - bf16_to_f(h.w));
      int byo = (m * 128 + (k4 << 1)) ^ ((m & 7) << 4);
      *(ushort4*)((char*)Ah + byo) = h;
      *(ushort4*)((char*)Al + byo) = l;
    }
    // ---- stage B: copy BN x 64 bf16 hi/lo from global (pre-split, [BN][K]) ----
#pragma unroll
    for (int it = 0; it < BN / 32; ++it) {
      int s = tid + it * 256;     // 16-byte slot
      int n = s >> 3;
      int kc = (s & 7) << 3;      // element offset (8 bf16 per slot)
      float4 vh = *(const float4*)(BTh + (size_t)n * K + kt + kc);
      float4 vl = *(const float4*)(BTl + (size_t)n * K + kt + kc);
      int byo = (n * 128 + (kc << 1)) ^ ((n & 7) << 4);
      *(float4*)((char*)Bh + byo) = vh;
      *(float4*)((char*)Bl + byo) = vl;
    }
    __syncthreads();
    // ---- MFMA over the two 32-k halves ----
#pragma unroll
    for (int ks = 0; ks < 2; ++ks) {
      int kb = ks * 64 + kgrp;
      short8 ah[2], al[2];
#pragma unroll
      for (int i = 0; i < 2; ++i) {
        int row = wm * 32 + i * 16 + l15;
        int off = (row * 128 + kb) ^ ((row & 7) << 4);
        ah[i] = *(const short8*)((const char*)Ah + off);
        al[i] = *(const short8*)((const char*)Al + off);
      }
#pragma unroll
      for (int j = 0; j < NT; ++j) {
        int nr = wn * WN + j * 16 + l15;
        int off = (nr * 128 + kb) ^ ((nr & 7) << 4);
        short8 bh = *(const short8*)((const char*)Bh + off);
        short8 bl = *(const short8*)((const char*)Bl + off);
#pragma unroll
        for (int i = 0; i < 2; ++i) {
          acc[i][j] = __builtin_amdgcn_mfma_f32_16x16x32_bf16(ah[i], bh, acc[i][j], 0, 0, 0);
          acc[i][j] = __builtin_amdgcn_mfma_f32_16x16x32_bf16(ah[i], bl, acc[i][j], 0, 0, 0);
          acc[i][j] = __builtin_amdgcn_mfma_f32_16x16x32_bf16(al[i], bh, acc[i][j], 0, 0, 0);
        }
      }
    }
    __syncthreads();
  }

  // ---- epilogue: C/D layout col=lane&15, row=(lane>>4)*4+q (m89) ----
  const int r4 = (lane >> 4) << 2;
#pragma unroll
  for (int i = 0; i < 2; ++i) {
    int rowb = bm + wm * 32 + i * 16 + r4;
#pragma unroll
    for (int j = 0; j < NT; ++j) {
      int col = wn * WN + j * 16 + l15;
#pragma unroll
      for (int q = 0; q < 4; ++q) {
        int row = rowb + q;
        if (row < N) C[(size_t)row * ldc + col] = acc[i][j][q];
      }
    }
  }
}

// ---------------- gather aggregation (CSR, float4/thread, unroll 4) ----------------

template <int LOGF, bool SMAX>
__global__ __launch_bounds__(256) void k_gather4(const float* __restrict__ t,
                                                 const int* __restrict__ row_ptr,
                                                 const int2* __restrict__ edge_s,
                                                 const float* __restrict__ dis,
                                                 const float* __restrict__ bias,
                                                 float* __restrict__ out, int ldo,
                                                 int coloff, int N) {
  constexpr int F = 1 << LOGF;
  constexpr int TPN = F / 4;
  int node = blockIdx.x * (256 / TPN) + threadIdx.x / TPN;
  if (node >= N) return;
  int f4 = (threadIdx.x % TPN) * 4;

  const float4 bv = *(const float4*)(bias + f4);
  const float dn = dis[node];
  const float dd = dn * dn;
  const float4 tv = *(const float4*)(t + (size_t)node * F + f4);
  float4 a0, a1;
  a0.x = bv.x + dd * tv.x; a0.y = bv.y + dd * tv.y;
  a0.z = bv.z + dd * tv.z; a0.w = bv.w + dd * tv.w;
  a1.x = a1.y = a1.z = a1.w = 0.f;

  const int beg = row_ptr[node], end = row_ptr[node + 1];
  int i = beg;
  for (; i + 4 <= end; i += 4) {
    int2 e0 = edge_s[i], e1 = edge_s[i + 1], e2 = edge_s[i + 2], e3 = edge_s[i + 3];
    float w0 = __int_as_float(e0.y), w1 = __int_as_float(e1.y);
    float w2 = __int_as_float(e2.y), w3 = __int_as_float(e3.y);
    float4 v0 = *(const float4*)(t + (size_t)e0.x * F + f4);
    float4 v1 = *(const float4*)(t + (size_t)e1.x * F + f4);
    float4 v2 = *(const float4*)(t + (size_t)e2.x * F + f4);
    float4 v3 = *(const float4*)(t + (size_t)e3.x * F + f4);
    a0.x += w0 * v0.x; a0.y += w0 * v0.y; a0.z += w0 * v0.z; a0.w += w0 * v0.w;
    a1.x += w1 * v1.x; a1.y += w1 * v1.y; a1.z += w1 * v1.z; a1.w += w1 * v1.w;
    a0.x += w2 * v2.x; a0.y += w2 * v2.y; a0.z += w2 * v2.z; a0.w += w2 * v2.w;
    a1.x += w3 * v3.x; a1.y += w3 * v3.y; a1.z += w3 * v3.z; a1.w += w3 * v3.w;
  }
  for (; i < end; ++i) {
    int2 e0 = edge_s[i];
    float w0 = __int_as_float(e0.y);
    float4 v0 = *(const float4*)(t + (size_t)e0.x * F + f4);
    a0.x += w0 * v0.x; a0.y += w0 * v0.y; a0.z += w0 * v0.z; a0.w += w0 * v0.w;
  }
  float4 v;
  v.x = a0.x + a1.x; v.y = a0.y + a1.y; v.z = a0.z + a1.z; v.w = a0.w + a1.w;

  if constexpr (SMAX) {
    float m = fmaxf(fmaxf(v.x, v.y), fmaxf(v.z, v.w));
#pragma unroll
    for (int o = 1; o < TPN; o <<= 1) m = fmaxf(m, __shfl_xor(m, o));
    v.x = __expf(v.x - m); v.y = __expf(v.y - m);
    v.z = __expf(v.z - m); v.w = __expf(v.w - m);
    float s = v.x + v.y + v.z + v.w;
#pragma unroll
    for (int o = 1; o < TPN; o <<= 1) s += __shfl_xor(s, o);
    float inv = 1.0f / s;
    v.x *= inv; v.y *= inv; v.z *= inv; v.w *= inv;
  }
  *(float4*)(out + (size_t)node * ldo + coloff + f4) = v;
}

// ---------------- fallback fp32 GEMM + atomic path (only if ws too small) ----------

__global__ __launch_bounds__(256) void k_gemm(const float* __restrict__ A, int lda,
                                              const float* __restrict__ B, int ldb,
                                              float* __restrict__ C, int ldc,
                                              int N, int K) {
  __shared__ float As[64][68];
  __shared__ float Bs[64][68];
  const int tid = threadIdx.x;
  const int bm = blockIdx.x * 64;
  const int bn = blockIdx.y * 64;
  const int tx = tid & 15;
  const int ty = tid >> 4;
  float acc[4][4] = {};
  for (int kt = 0; kt < K; kt += 64) {
#pragma unroll
    for (int p = 0; p < 4; ++p) {
      int s = tid + p * 256;
      int r = s >> 4;
      int c4 = (s & 15) << 2;
      float4 va = make_float4(0.f, 0.f, 0.f, 0.f);
      int gr = bm + r;
      if (gr < N) va = *(const float4*)(A + (size_t)gr * lda + kt + c4);
      As[c4 + 0][r] = va.x; As[c4 + 1][r] = va.y;
      As[c4 + 2][r] = va.z; As[c4 + 3][r] = va.w;
      float4 vb = *(const float4*)(B + (size_t)(kt + r) * ldb + bn + c4);
      *(float4*)(&Bs[r][c4]) = vb;
    }
    __syncthreads();
#pragma unroll
    for (int kk = 0; kk < 64; ++kk) {
      float4 a4 = *(const float4*)(&As[kk][ty * 4]);
      float4 b4 = *(const float4*)(&Bs[kk][tx * 4]);
      float a[4] = {a4.x, a4.y, a4.z, a4.w};
      float b[4] = {b4.x, b4.y, b4.z, b4.w};
#pragma unroll
      for (int i = 0; i < 4; ++i)
#pragma unroll
        for (int j = 0; j < 4; ++j) acc[i][j] += a[i] * b[j];
    }
    __syncthreads();
  }
#pragma unroll
  for (int i = 0; i < 4; ++i) {
    int gr = bm + ty * 4 + i;
    if (gr < N) {
      float4 v = make_float4(acc[i][0], acc[i][1], acc[i][2], acc[i][3]);
      *(float4*)(C + (size_t)gr * ldc + bn + tx * 4) = v;
    }
  }
}

__global__ __launch_bounds__(256) void k_deg_only(const int* __restrict__ dst,
                                                  const float* __restrict__ ew,
                                                  float* __restrict__ deg, int E) {
  int e = blockIdx.x * 256 + threadIdx.x;
  if (e < E) atomicAdd(&deg[dst[e]], ew[e]);
}

__global__ __launch_bounds__(256) void k_set1(float* __restrict__ p, int n) {
  int i = blockIdx.x * 256 + threadIdx.x;
  if (i < n) p[i] = 1.0f;
}

__global__ __launch_bounds__(256) void k_norm(const int* __restrict__ src,
                                              const int* __restrict__ dst,
                                              const float* __restrict__ ew,
                                              const float* __restrict__ dis,
                                              float* __restrict__ nrm, int E) {
  int e = blockIdx.x * 256 + threadIdx.x;
  if (e < E) nrm[e] = dis[src[e]] * ew[e] * dis[dst[e]];
}

template <int LOGF>
__global__ __launch_bounds__(256) void k_agg_init(const float* __restrict__ t,
                                                  const float* __restrict__ dis,
                                                  const float* __restrict__ bias,
                                                  float* __restrict__ out, int ldo,
                                                  int coloff, int n_total) {
  int idx = blockIdx.x * 256 + threadIdx.x;
  if (idx >= n_total) return;
  int n = idx >> LOGF;
  int f = idx & ((1 << LOGF) - 1);
  float d = dis[n];
  out[(size_t)n * ldo + coloff + f] = bias[f] + d * d * t[idx];
}

template <int LOGF>
__global__ __launch_bounds__(256) void k_agg_edges(const float* __restrict__ t,
                                                   const int* __restrict__ src,
                                                   const int* __restrict__ dst,
                                                   const float* __restrict__ nrm,
                                                   float* __restrict__ out, int ldo,
                                                   int coloff, int E) {
  constexpr int F = 1 << LOGF;
  constexpr int EPB = 256 >> LOGF;
  int e = blockIdx.x * EPB + (threadIdx.x >> LOGF);
  if (e >= E) return;
  int f = threadIdx.x & (F - 1);
  int s = src[e];
  int d = dst[e];
  float v = nrm[e] * t[(size_t)s * F + f];
  atomicAdd(&out[(size_t)d * ldo + coloff + f], v);
}

__global__ __launch_bounds__(256) void k_softmax128(float* __restrict__ h, int N) {
  int row = blockIdx.x * 4 + (threadIdx.x >> 6);
  if (row >= N) return;
  int lane = threadIdx.x & 63;
  float* p = h + (size_t)row * 128;
  float v0 = p[lane];
  float v1 = p[lane + 64];
  float m = fmaxf(v0, v1);
#pragma unroll
  for (int o = 32; o > 0; o >>= 1) m = fmaxf(m, __shfl_xor(m, o));
  float e0 = __expf(v0 - m);
  float e1 = __expf(v1 - m);
  float sum = e0 + e1;
#pragma unroll
  for (int o = 32; o > 0; o >>= 1) sum += __shfl_xor(sum, o);
  float inv = 1.0f / sum;
  p[lane] = e0 * inv;
  p[lane + 64] = e1 * inv;
}

// ---------------- launch ----------------
extern "C" void kernel_launch(void* const* d_in, const int* in_sizes, int n_in,
                              void* d_out, int out_size, void* d_ws, size_t ws_size,
                              hipStream_t stream) {
  const float* x = (const float*)d_in[0];
  const int* ei = (const int*)d_in[1];  // integer inputs arrive as int32
  const float* ea = (const float*)d_in[2];
  const float* W1 = (const float*)d_in[3];
  const float* b1 = (const float*)d_in[4];
  const float* W2 = (const float*)d_in[5];
  const float* b2 = (const float*)d_in[6];
  const float* W3 = (const float*)d_in[7];
  const float* b3 = (const float*)d_in[8];

  const int N = NN;
  const int E = in_sizes[2];
  const int* src = ei;
  const int* dst = ei + E;

  char* ws = (char*)d_ws;
  size_t off = 0;
  auto alloc = [&](size_t bytes) {
    void* p = (void*)(ws + off);
    off += (bytes + 255) & ~(size_t)255;
    return p;
  };

  float* dis = (float*)alloc((size_t)N * 4);
  int* row_ptr = (int*)alloc((size_t)(N + 1) * 4);
  int* cnt = (int*)alloc((size_t)N * 4);
  int* bsum = (int*)alloc(256 * 4);
  int2* edge_s = (int2*)alloc((size_t)E * 8);
  float* t12 = (float*)alloc((size_t)N * 128 * 4);
  float* H = (float*)alloc((size_t)N * 128 * 4);
  ushort* w1h = (ushort*)alloc((size_t)512 * 64 * 2);
  ushort* w1l = (ushort*)alloc((size_t)512 * 64 * 2);
  ushort* w2h = (ushort*)alloc((size_t)64 * 64 * 2);
  ushort* w2l = (ushort*)alloc((size_t)64 * 64 * 2);
  ushort* w3h = (ushort*)alloc((size_t)128 * 128 * 2);
  ushort* w3l = (ushort*)alloc((size_t)128 * 128 * 2);
  size_t need_sort = off;
  float* out = (float*)d_out;

  const bool useSort = (ws_size >= need_sort);
  const int NB_SCAN = (N + 1023) / 1024;
  const int GM = (N + 63) / 64;  // 782

  if (useSort) {
    // ---- weight pre-split (independent of graph preprocessing) ----
    k_wsplit<<<(512 * 64 + 255) / 256, 256, 0, stream>>>(W1, 6, 512, w1h, w1l, 512 * 64);
    k_wsplit<<<(64 * 64 + 255) / 256, 256, 0, stream>>>(W2, 6, 64, w2h, w2l, 64 * 64);
    k_wsplit<<<(128 * 128 + 255) / 256, 256, 0, stream>>>(W3, 7, 128, w3h, w3l, 128 * 128);

    // ---- CSR-by-dst preprocessing ----
    k_init<<<(N + 255) / 256, 256, 0, stream>>>(dis, cnt, N);
    k_deg_hist<<<(E + 255) / 256, 256, 0, stream>>>(dst, ea, dis, cnt, E);
    k_rsqrt<<<(N + 255) / 256, 256, 0, stream>>>(dis, N);
    k_scan1<<<NB_SCAN, 256, 0, stream>>>(cnt, row_ptr, bsum, N);
    k_scan2<<<1, 64, 0, stream>>>(bsum, NB_SCAN);
    k_scan3<<<(N + 255) / 256, 256, 0, stream>>>(row_ptr, bsum, N);
    k_seti<<<1, 1, 0, stream>>>(row_ptr + N, E);
    k_zero_int<<<(N + 255) / 256, 256, 0, stream>>>(cnt, N);
    k_scatter<<<(E + 255) / 256, 256, 0, stream>>>(src, dst, ea, dis, row_ptr, cnt,
                                                   edge_s, E);

    // conv1: t1 = x @ W1 ; h1 -> H[:,0:64]
    k_gemm_mfma<64><<<GM, 256, 0, stream>>>(x, 512, w1h, w1l, t12, 64, N, 512);
    k_gather4<6, false><<<(N + 15) / 16, 256, 0, stream>>>(t12, row_ptr, edge_s, dis,
                                                           b1, H, 128, 0, N);
    // conv2: t2 = h1 @ W2 ; h2 -> H[:,64:128]
    k_gemm_mfma<64><<<GM, 256, 0, stream>>>(H, 128, w2h, w2l, t12, 64, N, 64);
    k_gather4<6, false><<<(N + 15) / 16, 256, 0, stream>>>(t12, row_ptr, edge_s, dis,
                                                           b2, H, 128, 64, N);
    // conv3: t3 = [h1,h2] @ W3 ; softmax(A t3 + b3) -> d_out (fused)
    k_gemm_mfma<128><<<GM, 256, 0, stream>>>(H, 128, w3h, w3l, t12, 128, N, 128);
    k_gather4<7, true><<<(N + 7) / 8, 256, 0, stream>>>(t12, row_ptr, edge_s, dis,
                                                        b3, out, 128, 0, N);
  } else {
    // ---- fallback: fp32 GEMM + atomic scatter path ----
    off = 0;
    dis = (float*)alloc((size_t)N * 4);
    float* nrm = (float*)alloc((size_t)E * 4);
    t12 = (float*)alloc((size_t)N * 128 * 4);
    H = (float*)alloc((size_t)N * 128 * 4);
    const int tot64 = N * 64, tot128 = N * 128;
    dim3 g64(GM, 1), g128(GM, 2);

    k_set1<<<(N + 255) / 256, 256, 0, stream>>>(dis, N);
    k_deg_only<<<(E + 255) / 256, 256, 0, stream>>>(dst, ea, dis, E);
    k_rsqrt<<<(N + 255) / 256, 256, 0, stream>>>(dis, N);
    k_norm<<<(E + 255) / 256, 256, 0, stream>>>(src, dst, ea, dis, nrm, E);

    k_gemm<<<g64, 256, 0, stream>>>(x, 512, W1, 64, t12, 64, N, 512);
    k_agg_init<6><<<(tot64 + 255) / 256, 256, 0, stream>>>(t12, dis, b1, H, 128, 0, tot64);
    k_agg_edges<6><<<(E + 3) / 4, 256, 0, stream>>>(t12, src, dst, nrm, H, 128, 0, E);

    k_gemm<<<g64, 256, 0, stream>>>(H, 128, W2, 64, t12, 64, N, 64);
    k_agg_init<6><<<(tot64 + 255) / 256, 256, 0, stream>>>(t12, dis, b2, H, 128, 64, tot64);
    k_agg_edges<6><<<(E + 3) / 4, 256, 0, stream>>>(t12, src, dst, nrm, H, 128, 64, E);

    k_gemm<<<g128, 256, 0, stream>>>(H, 128, W3, 128, t12, 128, N, 128);
    k_agg_init<7><<<(tot128 + 255) / 256, 256, 0, stream>>>(t12, dis, b3, out, 128, 0, tot128);
    k_agg_edges<7><<<(E + 1) / 2, 256, 0, stream>>>(t12, src, dst, nrm, out, 128, 0, E);

    k_softmax128<<<(N + 3) / 4, 256, 0, stream>>>(out, N);
  }
}

// Round 6
// 267.051 us; speedup vs baseline: 3.3976x; 1.1745x over previous
//
#include <hip/hip_runtime.h>
#include <cstdint>
#include <cstddef>

#define NN 50000

typedef __attribute__((ext_vector_type(8))) short short8;
typedef __attribute__((ext_vector_type(4))) float f32x4;

__device__ inline ushort bf16_rne(float x) {
  uint u = __float_as_uint(x);
  uint r = u + 0x7FFFu + ((u >> 16) & 1u);
  return (ushort)(r >> 16);
}
__device__ inline float bf16_to_f(ushort h) { return __uint_as_float(((uint)h) << 16); }

// ---------------- CSR build, atomic-free (global) ----------------
// Nodes split into NSLICE slices of SL; B blocks per slice, each owning an edge chunk.

#define SL 12500
#define NSL 4
#define NB 64

// per-(slice,block) LDS histogram of dst -> histmat[(s*NB+b)*SL + nl]
__global__ __launch_bounds__(256) void k_hist_slice(const int* __restrict__ dst,
                                                    int* __restrict__ histmat, int E) {
  __shared__ int lcnt[SL];
  const int s = blockIdx.x / NB, b = blockIdx.x % NB;
  for (int i = threadIdx.x; i < SL; i += 256) lcnt[i] = 0;
  __syncthreads();
  const int lo = s * SL;
  const int e0 = (int)((long long)E * b / NB);
  const int e1 = (int)((long long)E * (b + 1) / NB);
  for (int e = e0 + threadIdx.x; e < e1; e += 256) {
    int d = dst[e] - lo;
    if ((unsigned)d < (unsigned)SL) atomicAdd(&lcnt[d], 1);
  }
  __syncthreads();
  int* out = histmat + (size_t)blockIdx.x * SL;
  for (int i = threadIdx.x; i < SL; i += 256) out[i] = lcnt[i];
}

// per-node prefix over the NB blocks: histmat -> exclusive bases; cnt[n] = total
__global__ __launch_bounds__(256) void k_colscan(int* __restrict__ histmat,
                                                 int* __restrict__ cnt, int N) {
  int n = blockIdx.x * 256 + threadIdx.x;
  if (n >= N) return;
  int s = n / SL, nl = n % SL;
  int* base = histmat + (size_t)s * NB * SL + nl;
  int run = 0;
#pragma unroll 8
  for (int b = 0; b < NB; ++b) {
    int t = base[(size_t)b * SL];
    base[(size_t)b * SL] = run;
    run += t;
  }
  cnt[n] = run;
}

// scatter edges into dst-sorted order; LDS-local cursors only
__global__ __launch_bounds__(256) void k_scatter_slice(const int* __restrict__ src,
                                                       const int* __restrict__ dst,
                                                       const float* __restrict__ ew,
                                                       const int* __restrict__ row_ptr,
                                                       const int* __restrict__ histmat,
                                                       int2* __restrict__ edge_s, int E) {
  __shared__ int lcur[SL];
  const int s = blockIdx.x / NB, b = blockIdx.x % NB;
  for (int i = threadIdx.x; i < SL; i += 256) lcur[i] = 0;
  __syncthreads();
  const int lo = s * SL;
  const int* hb = histmat + (size_t)blockIdx.x * SL;
  const int e0 = (int)((long long)E * b / NB);
  const int e1 = (int)((long long)E * (b + 1) / NB);
  for (int e = e0 + threadIdx.x; e < e1; e += 256) {
    int d = dst[e] - lo;
    if ((unsigned)d < (unsigned)SL) {
      int pos = row_ptr[d + lo] + hb[d] + atomicAdd(&lcur[d], 1);
      edge_s[pos] = make_int2(src[e], __float_as_int(ew[e]));
    }
  }
}

// deg[n] = 1 + sum of ew over CSR row; dis = rsqrt(deg)  (fused)
__global__ __launch_bounds__(256) void k_degsum(const int* __restrict__ row_ptr,
                                                const int2* __restrict__ edge_s,
                                                float* __restrict__ dis, int N) {
  int n = blockIdx.x * 256 + threadIdx.x;
  if (n >= N) return;
  float sum = 1.0f;
  int e1 = row_ptr[n + 1];
  for (int p = row_ptr[n]; p < e1; ++p) sum += __int_as_float(edge_s[p].y);
  dis[n] = rsqrtf(sum);
}

// edge weight finalize: w' = dis[src] * ew   (dis[dst] factored into gather epilogue)
__global__ __launch_bounds__(256) void k_wfix(int2* __restrict__ edge_s,
                                              const float* __restrict__ dis, int E) {
  int p = blockIdx.x * 256 + threadIdx.x;
  if (p >= E) return;
  int2 v = edge_s[p];
  edge_s[p] = make_int2(v.x, __float_as_int(dis[v.x] * __int_as_float(v.y)));
}

// ---------------- exclusive scan over int[n] (1024 elems / block) ----------------

__global__ __launch_bounds__(256) void k_scan1(const int* __restrict__ in,
                                               int* __restrict__ out,
                                               int* __restrict__ bsum, int n) {
  __shared__ int ts[256];
  int base = blockIdx.x * 1024 + threadIdx.x * 4;
  int v[4] = {0, 0, 0, 0};
#pragma unroll
  for (int j = 0; j < 4; ++j) { int i = base + j; if (i < n) v[j] = in[i]; }
  int s = v[0] + v[1] + v[2] + v[3];
  ts[threadIdx.x] = s;
  __syncthreads();
  for (int o = 1; o < 256; o <<= 1) {
    int t = (threadIdx.x >= o) ? ts[threadIdx.x - o] : 0;
    __syncthreads();
    ts[threadIdx.x] += t;
    __syncthreads();
  }
  int run = ts[threadIdx.x] - s;
#pragma unroll
  for (int j = 0; j < 4; ++j) { int i = base + j; if (i < n) out[i] = run; run += v[j]; }
  if (threadIdx.x == 255) bsum[blockIdx.x] = ts[255];
}

__global__ void k_scan2(int* __restrict__ bsum, int nb) {
  if (threadIdx.x == 0) {
    int run = 0;
    for (int b = 0; b < nb; ++b) { int t = bsum[b]; bsum[b] = run; run += t; }
  }
}

__global__ __launch_bounds__(256) void k_scan3(int* __restrict__ out,
                                               const int* __restrict__ bsum, int n) {
  int i = blockIdx.x * 256 + threadIdx.x;
  if (i < n) out[i] += bsum[i >> 10];
}

__global__ void k_seti(int* __restrict__ p, int v) { *p = v; }

// W[k][n] fp32  ->  WT_hi[n][k], WT_lo[n][k] bf16 (split)
__global__ __launch_bounds__(256) void k_wsplit(const float* __restrict__ W, int logF,
                                                int K, ushort* __restrict__ th,
                                                ushort* __restrict__ tl, int total) {
  int idx = blockIdx.x * 256 + threadIdx.x;
  if (idx >= total) return;
  int k = idx >> logF;
  int n = idx & ((1 << logF) - 1);
  float w = W[idx];
  ushort h = bf16_rne(w);
  float lof = w - bf16_to_f(h);
  ushort l = bf16_rne(lof);
  th[(size_t)n * K + k] = h;
  tl[(size_t)n * K + k] = l;
}

// ---------------- split-bf16 MFMA GEMM: C[N,BN] = A[N,K] @ B[K,BN] ----------------

template <int BN>
__global__ __launch_bounds__(256) void k_gemm_mfma(const float* __restrict__ A, int lda,
                                                   const ushort* __restrict__ BTh,
                                                   const ushort* __restrict__ BTl,
                                                   float* __restrict__ C, int ldc,
                                                   int N, int K) {
  constexpr int WN = BN / 2;
  constexpr int NT = WN / 16;
  __shared__ __align__(16) ushort Ah[64 * 64];
  __shared__ __align__(16) ushort Al[64 * 64];
  __shared__ __align__(16) ushort Bh[BN * 64];
  __shared__ __align__(16) ushort Bl[BN * 64];

  const int tid = threadIdx.x;
  const int lane = tid & 63;
  const int wid = tid >> 6;
  const int wm = wid >> 1;
  const int wn = wid & 1;
  const int bm = blockIdx.x * 64;
  const int l15 = lane & 15;
  const int kgrp = (lane >> 4) << 4;

  f32x4 acc[2][NT] = {};

  for (int kt = 0; kt < K; kt += 64) {
#pragma unroll
    for (int p = 0; p < 4; ++p) {
      int s = tid + p * 256;
      int m = s >> 4;
      int k4 = (s & 15) << 2;
      int gr = bm + m;
      float4 v = make_float4(0.f, 0.f, 0.f, 0.f);
      if (gr < N) v = *(const float4*)(A + (size_t)gr * lda + kt + k4);
      ushort4 h, l;
      h.x = bf16_rne(v.x); l.x = bf16_rne(v.x - bf16_to_f(h.x));
      h.y = bf16_rne(v.y); l.y = bf16_rne(v.y - bf16_to_f(h.y));
      h.z = bf16_rne(v.z); l.z = bf16_rne(v.z - bf16_to_f(h.z));
      h.w = bf16_rne(v.w); l.w = bf16_rne(v.w - bf16_to_f(h.w));
      int byo = (m * 128 + (k4 << 1)) ^ ((m & 7) << 4);
      *(ushort4*)((char*)Ah + byo) = h;
      *(ushort4*)((char*)Al + byo) = l;
    }
#pragma unroll
    for (int it = 0; it < BN / 32; ++it) {
      int s = tid + it * 256;
      int n = s >> 3;
      int kc = (s & 7) << 3;
      float4 vh = *(const float4*)(BTh + (size_t)n * K + kt + kc);
      float4 vl = *(const float4*)(BTl + (size_t)n * K + kt + kc);
      int byo = (n * 128 + (kc << 1)) ^ ((n & 7) << 4);
      *(float4*)((char*)Bh + byo) = vh;
      *(float4*)((char*)Bl + byo) = vl;
    }
    __syncthreads();
#pragma unroll
    for (int ks = 0; ks < 2; ++ks) {
      int kb = ks * 64 + kgrp;
      short8 ah[2], al[2];
#pragma unroll
      for (int i = 0; i < 2; ++i) {
        int row = wm * 32 + i * 16 + l15;
        int off = (row * 128 + kb) ^ ((row & 7) << 4);
        ah[i] = *(const short8*)((const char*)Ah + off);
        al[i] = *(const short8*)((const char*)Al + off);
      }
#pragma unroll
      for (int j = 0; j < NT; ++j) {
        int nr = wn * WN + j * 16 + l15;
        int off = (nr * 128 + kb) ^ ((nr & 7) << 4);
        short8 bh = *(const short8*)((const char*)Bh + off);
        short8 bl = *(const short8*)((const char*)Bl + off);
#pragma unroll
        for (int i = 0; i < 2; ++i) {
          acc[i][j] = __builtin_amdgcn_mfma_f32_16x16x32_bf16(ah[i], bh, acc[i][j], 0, 0, 0);
          acc[i][j] = __builtin_amdgcn_mfma_f32_16x16x32_bf16(ah[i], bl, acc[i][j], 0, 0, 0);
          acc[i][j] = __builtin_amdgcn_mfma_f32_16x16x32_bf16(al[i], bh, acc[i][j], 0, 0, 0);
        }
      }
    }
    __syncthreads();
  }

  const int r4 = (lane >> 4) << 2;
#pragma unroll
  for (int i = 0; i < 2; ++i) {
    int rowb = bm + wm * 32 + i * 16 + r4;
#pragma unroll
    for (int j = 0; j < NT; ++j) {
      int col = wn * WN + j * 16 + l15;
#pragma unroll
      for (int q = 0; q < 4; ++q) {
        int row = rowb + q;
        if (row < N) C[(size_t)row * ldc + col] = acc[i][j][q];
      }
    }
  }
}

// ---------------- gather aggregation (CSR, float4/thread, unroll 4) ----------------
// out[n,f] = bias[f] + dis[n]^2 * t[n,f] + dis[n] * sum_i w'_i * t[s_i,f],  w' = dis_s*ew

template <int LOGF, bool SMAX>
__global__ __launch_bounds__(256) void k_gather4(const float* __restrict__ t,
                                                 const int* __restrict__ row_ptr,
                                                 const int2* __restrict__ edge_s,
                                                 const float* __restrict__ dis,
                                                 const float* __restrict__ bias,
                                                 float* __restrict__ out, int ldo,
                                                 int coloff, int N) {
  constexpr int F = 1 << LOGF;
  constexpr int TPN = F / 4;
  int node = blockIdx.x * (256 / TPN) + threadIdx.x / TPN;
  if (node >= N) return;
  int f4 = (threadIdx.x % TPN) * 4;

  const float4 bv = *(const float4*)(bias + f4);
  const float dn = dis[node];
  const float dd = dn * dn;
  const float4 tv = *(const float4*)(t + (size_t)node * F + f4);
  float4 a0, a1;
  a0.x = a0.y = a0.z = a0.w = 0.f;
  a1.x = a1.y = a1.z = a1.w = 0.f;

  const int beg = row_ptr[node], end = row_ptr[node + 1];
  int i = beg;
  for (; i + 4 <= end; i += 4) {
    int2 e0 = edge_s[i], e1 = edge_s[i + 1], e2 = edge_s[i + 2], e3 = edge_s[i + 3];
    float w0 = __int_as_float(e0.y), w1 = __int_as_float(e1.y);
    float w2 = __int_as_float(e2.y), w3 = __int_as_float(e3.y);
    float4 v0 = *(const float4*)(t + (size_t)e0.x * F + f4);
    float4 v1 = *(const float4*)(t + (size_t)e1.x * F + f4);
    float4 v2 = *(const float4*)(t + (size_t)e2.x * F + f4);
    float4 v3 = *(const float4*)(t + (size_t)e3.x * F + f4);
    a0.x += w0 * v0.x; a0.y += w0 * v0.y; a0.z += w0 * v0.z; a0.w += w0 * v0.w;
    a1.x += w1 * v1.x; a1.y += w1 * v1.y; a1.z += w1 * v1.z; a1.w += w1 * v1.w;
    a0.x += w2 * v2.x; a0.y += w2 * v2.y; a0.z += w2 * v2.z; a0.w += w2 * v2.w;
    a1.x += w3 * v3.x; a1.y += w3 * v3.y; a1.z += w3 * v3.z; a1.w += w3 * v3.w;
  }
  for (; i < end; ++i) {
    int2 e0 = edge_s[i];
    float w0 = __int_as_float(e0.y);
    float4 v0 = *(const float4*)(t + (size_t)e0.x * F + f4);
    a0.x += w0 * v0.x; a0.y += w0 * v0.y; a0.z += w0 * v0.z; a0.w += w0 * v0.w;
  }
  float4 v;
  v.x = bv.x + dd * tv.x + dn * (a0.x + a1.x);
  v.y = bv.y + dd * tv.y + dn * (a0.y + a1.y);
  v.z = bv.z + dd * tv.z + dn * (a0.z + a1.z);
  v.w = bv.w + dd * tv.w + dn * (a0.w + a1.w);

  if constexpr (SMAX) {
    float m = fmaxf(fmaxf(v.x, v.y), fmaxf(v.z, v.w));
#pragma unroll
    for (int o = 1; o < TPN; o <<= 1) m = fmaxf(m, __shfl_xor(m, o));
    v.x = __expf(v.x - m); v.y = __expf(v.y - m);
    v.z = __expf(v.z - m); v.w = __expf(v.w - m);
    float s = v.x + v.y + v.z + v.w;
#pragma unroll
    for (int o = 1; o < TPN; o <<= 1) s += __shfl_xor(s, o);
    float inv = 1.0f / s;
    v.x *= inv; v.y *= inv; v.z *= inv; v.w *= inv;
  }
  *(float4*)(out + (size_t)node * ldo + coloff + f4) = v;
}

// ---------------- fallback fp32 GEMM + atomic path (only if ws too small) ----------

__global__ __launch_bounds__(256) void k_gemm(const float* __restrict__ A, int lda,
                                              const float* __restrict__ B, int ldb,
                                              float* __restrict__ C, int ldc,
                                              int N, int K) {
  __shared__ float As[64][68];
  __shared__ float Bs[64][68];
  const int tid = threadIdx.x;
  const int bm = blockIdx.x * 64;
  const int bn = blockIdx.y * 64;
  const int tx = tid & 15;
  const int ty = tid >> 4;
  float acc[4][4] = {};
  for (int kt = 0; kt < K; kt += 64) {
#pragma unroll
    for (int p = 0; p < 4; ++p) {
      int s = tid + p * 256;
      int r = s >> 4;
      int c4 = (s & 15) << 2;
      float4 va = make_float4(0.f, 0.f, 0.f, 0.f);
      int gr = bm + r;
      if (gr < N) va = *(const float4*)(A + (size_t)gr * lda + kt + c4);
      As[c4 + 0][r] = va.x; As[c4 + 1][r] = va.y;
      As[c4 + 2][r] = va.z; As[c4 + 3][r] = va.w;
      float4 vb = *(const float4*)(B + (size_t)(kt + r) * ldb + bn + c4);
      *(float4*)(&Bs[r][c4]) = vb;
    }
    __syncthreads();
#pragma unroll
    for (int kk = 0; kk < 64; ++kk) {
      float4 a4 = *(const float4*)(&As[kk][ty * 4]);
      float4 b4 = *(const float4*)(&Bs[kk][tx * 4]);
      float a[4] = {a4.x, a4.y, a4.z, a4.w};
      float b[4] = {b4.x, b4.y, b4.z, b4.w};
#pragma unroll
      for (int i = 0; i < 4; ++i)
#pragma unroll
        for (int j = 0; j < 4; ++j) acc[i][j] += a[i] * b[j];
    }
    __syncthreads();
  }
#pragma unroll
  for (int i = 0; i < 4; ++i) {
    int gr = bm + ty * 4 + i;
    if (gr < N) {
      float4 v = make_float4(acc[i][0], acc[i][1], acc[i][2], acc[i][3]);
      *(float4*)(C + (size_t)gr * ldc + bn + tx * 4) = v;
    }
  }
}

__global__ __launch_bounds__(256) void k_deg_only(const int* __restrict__ dst,
                                                  const float* __restrict__ ew,
                                                  float* __restrict__ deg, int E) {
  int e = blockIdx.x * 256 + threadIdx.x;
  if (e < E) atomicAdd(&deg[dst[e]], ew[e]);
}

__global__ __launch_bounds__(256) void k_set1(float* __restrict__ p, int n) {
  int i = blockIdx.x * 256 + threadIdx.x;
  if (i < n) p[i] = 1.0f;
}

__global__ __launch_bounds__(256) void k_rsqrt(float* __restrict__ p, int n) {
  int i = blockIdx.x * 256 + threadIdx.x;
  if (i < n) p[i] = rsqrtf(p[i]);
}

__global__ __launch_bounds__(256) void k_norm(const int* __restrict__ src,
                                              const int* __restrict__ dst,
                                              const float* __restrict__ ew,
                                              const float* __restrict__ dis,
                                              float* __restrict__ nrm, int E) {
  int e = blockIdx.x * 256 + threadIdx.x;
  if (e < E) nrm[e] = dis[src[e]] * ew[e] * dis[dst[e]];
}

template <int LOGF>
__global__ __launch_bounds__(256) void k_agg_init(const float* __restrict__ t,
                                                  const float* __restrict__ dis,
                                                  const float* __restrict__ bias,
                                                  float* __restrict__ out, int ldo,
                                                  int coloff, int n_total) {
  int idx = blockIdx.x * 256 + threadIdx.x;
  if (idx >= n_total) return;
  int n = idx >> LOGF;
  int f = idx & ((1 << LOGF) - 1);
  float d = dis[n];
  out[(size_t)n * ldo + coloff + f] = bias[f] + d * d * t[idx];
}

template <int LOGF>
__global__ __launch_bounds__(256) void k_agg_edges(const float* __restrict__ t,
                                                   const int* __restrict__ src,
                                                   const int* __restrict__ dst,
                                                   const float* __restrict__ nrm,
                                                   float* __restrict__ out, int ldo,
                                                   int coloff, int E) {
  constexpr int F = 1 << LOGF;
  constexpr int EPB = 256 >> LOGF;
  int e = blockIdx.x * EPB + (threadIdx.x >> LOGF);
  if (e >= E) return;
  int f = threadIdx.x & (F - 1);
  int s = src[e];
  int d = dst[e];
  float v = nrm[e] * t[(size_t)s * F + f];
  atomicAdd(&out[(size_t)d * ldo + coloff + f], v);
}

__global__ __launch_bounds__(256) void k_softmax128(float* __restrict__ h, int N) {
  int row = blockIdx.x * 4 + (threadIdx.x >> 6);
  if (row >= N) return;
  int lane = threadIdx.x & 63;
  float* p = h + (size_t)row * 128;
  float v0 = p[lane];
  float v1 = p[lane + 64];
  float m = fmaxf(v0, v1);
#pragma unroll
  for (int o = 32; o > 0; o >>= 1) m = fmaxf(m, __shfl_xor(m, o));
  float e0 = __expf(v0 - m);
  float e1 = __expf(v1 - m);
  float sum = e0 + e1;
#pragma unroll
  for (int o = 32; o > 0; o >>= 1) sum += __shfl_xor(sum, o);
  float inv = 1.0f / sum;
  p[lane] = e0 * inv;
  p[lane + 64] = e1 * inv;
}

// ---------------- launch ----------------
extern "C" void kernel_launch(void* const* d_in, const int* in_sizes, int n_in,
                              void* d_out, int out_size, void* d_ws, size_t ws_size,
                              hipStream_t stream) {
  const float* x = (const float*)d_in[0];
  const int* ei = (const int*)d_in[1];  // integer inputs arrive as int32
  const float* ea = (const float*)d_in[2];
  const float* W1 = (const float*)d_in[3];
  const float* b1 = (const float*)d_in[4];
  const float* W2 = (const float*)d_in[5];
  const float* b2 = (const float*)d_in[6];
  const float* W3 = (const float*)d_in[7];
  const float* b3 = (const float*)d_in[8];

  const int N = NN;
  const int E = in_sizes[2];
  const int* src = ei;
  const int* dst = ei + E;

  char* ws = (char*)d_ws;
  size_t off = 0;
  auto alloc = [&](size_t bytes) {
    void* p = (void*)(ws + off);
    off += (bytes + 255) & ~(size_t)255;
    return p;
  };

  float* dis = (float*)alloc((size_t)N * 4);
  int* row_ptr = (int*)alloc((size_t)(N + 1) * 4);
  int* cnt = (int*)alloc((size_t)N * 4);
  int* bsum = (int*)alloc(256 * 4);
  int2* edge_s = (int2*)alloc((size_t)E * 8);
  float* t12 = (float*)alloc((size_t)N * 128 * 4);
  float* H = (float*)alloc((size_t)N * 128 * 4);
  ushort* w1h = (ushort*)alloc((size_t)512 * 64 * 2);
  ushort* w1l = (ushort*)alloc((size_t)512 * 64 * 2);
  ushort* w2h = (ushort*)alloc((size_t)64 * 64 * 2);
  ushort* w2l = (ushort*)alloc((size_t)64 * 64 * 2);
  ushort* w3h = (ushort*)alloc((size_t)128 * 128 * 2);
  ushort* w3l = (ushort*)alloc((size_t)128 * 128 * 2);
  size_t need_sort = off;
  float* out = (float*)d_out;
  // histmat (NSL*NB*SL ints = 12.8 MB) aliases H, which is dead until conv1's gather
  int* histmat = (int*)H;

  const bool useSort = (ws_size >= need_sort);
  const int NB_SCAN = (N + 1023) / 1024;
  const int GM = (N + 63) / 64;

  if (useSort) {
    // ---- weight pre-split ----
    k_wsplit<<<(512 * 64 + 255) / 256, 256, 0, stream>>>(W1, 6, 512, w1h, w1l, 512 * 64);
    k_wsplit<<<(64 * 64 + 255) / 256, 256, 0, stream>>>(W2, 6, 64, w2h, w2l, 64 * 64);
    k_wsplit<<<(128 * 128 + 255) / 256, 256, 0, stream>>>(W3, 7, 128, w3h, w3l, 128 * 128);

    // ---- CSR-by-dst, atomic-free ----
    k_hist_slice<<<NSL * NB, 256, 0, stream>>>(dst, histmat, E);
    k_colscan<<<(N + 255) / 256, 256, 0, stream>>>(histmat, cnt, N);
    k_scan1<<<NB_SCAN, 256, 0, stream>>>(cnt, row_ptr, bsum, N);
    k_scan2<<<1, 64, 0, stream>>>(bsum, NB_SCAN);
    k_scan3<<<(N + 255) / 256, 256, 0, stream>>>(row_ptr, bsum, N);
    k_seti<<<1, 1, 0, stream>>>(row_ptr + N, E);
    k_scatter_slice<<<NSL * NB, 256, 0, stream>>>(src, dst, ea, row_ptr, histmat,
                                                  edge_s, E);
    k_degsum<<<(N + 255) / 256, 256, 0, stream>>>(row_ptr, edge_s, dis, N);
    k_wfix<<<(E + 255) / 256, 256, 0, stream>>>(edge_s, dis, E);

    // conv1: t1 = x @ W1 ; h1 -> H[:,0:64]
    k_gemm_mfma<64><<<GM, 256, 0, stream>>>(x, 512, w1h, w1l, t12, 64, N, 512);
    k_gather4<6, false><<<(N + 15) / 16, 256, 0, stream>>>(t12, row_ptr, edge_s, dis,
                                                           b1, H, 128, 0, N);
    // conv2: t2 = h1 @ W2 ; h2 -> H[:,64:128]
    k_gemm_mfma<64><<<GM, 256, 0, stream>>>(H, 128, w2h, w2l, t12, 64, N, 64);
    k_gather4<6, false><<<(N + 15) / 16, 256, 0, stream>>>(t12, row_ptr, edge_s, dis,
                                                           b2, H, 128, 64, N);
    // conv3: t3 = [h1,h2] @ W3 ; softmax(A t3 + b3) -> d_out (fused)
    k_gemm_mfma<128><<<GM, 256, 0, stream>>>(H, 128, w3h, w3l, t12, 128, N, 128);
    k_gather4<7, true><<<(N + 7) / 8, 256, 0, stream>>>(t12, row_ptr, edge_s, dis,
                                                        b3, out, 128, 0, N);
  } else {
    // ---- fallback: fp32 GEMM + atomic scatter path ----
    off = 0;
    dis = (float*)alloc((size_t)N * 4);
    float* nrm = (float*)alloc((size_t)E * 4);
    t12 = (float*)alloc((size_t)N * 128 * 4);
    H = (float*)alloc((size_t)N * 128 * 4);
    const int tot64 = N * 64, tot128 = N * 128;
    dim3 g64(GM, 1), g128(GM, 2);

    k_set1<<<(N + 255) / 256, 256, 0, stream>>>(dis, N);
    k_deg_only<<<(E + 255) / 256, 256, 0, stream>>>(dst, ea, dis, E);
    k_rsqrt<<<(N + 255) / 256, 256, 0, stream>>>(dis, N);
    k_norm<<<(E + 255) / 256, 256, 0, stream>>>(src, dst, ea, dis, nrm, E);

    k_gemm<<<g64, 256, 0, stream>>>(x, 512, W1, 64, t12, 64, N, 512);
    k_agg_init<6><<<(tot64 + 255) / 256, 256, 0, stream>>>(t12, dis, b1, H, 128, 0, tot64);
    k_agg_edges<6><<<(E + 3) / 4, 256, 0, stream>>>(t12, src, dst, nrm, H, 128, 0, E);

    k_gemm<<<g64, 256, 0, stream>>>(H, 128, W2, 64, t12, 64, N, 64);
    k_agg_init<6><<<(tot64 + 255) / 256, 256, 0, stream>>>(t12, dis, b2, H, 128, 64, tot64);
    k_agg_edges<6><<<(E + 3) / 4, 256, 0, stream>>>(t12, src, dst, nrm, H, 128, 64, E);

    k_gemm<<<g128, 256, 0, stream>>>(H, 128, W3, 128, t12, 128, N, 128);
    k_agg_init<7><<<(tot128 + 255) / 256, 256, 0, stream>>>(t12, dis, b3, out, 128, 0, tot128);
    k_agg_edges<7><<<(E + 1) / 2, 256, 0, stream>>>(t12, src, dst, nrm, out, 128, 0, E);

    k_softmax128<<<(N + 3) / 4, 256, 0, stream>>>(out, N);
  }
}